// Round 8
// baseline (232.079 us; speedup 1.0000x reference)
//
#include <hip/hip_runtime.h>
#include <hip/hip_bf16.h>

// LSTM_80960133529703: B=16384, T=24, F=7, H=8, L=4; dense 192->1024->2048->4.
// R16: pre_kernel LSTM de-latencied (gemm2/dense1-tail/wcvt frozen at R15):
//  (1) xs LDS staging dropped -> x read from global (L2-resident, off-chain).
//      LDS 47104->25600 B => blocks/CU 3 -> ~5-6 (2x latency-hiding waves).
//  (2) zx pipelining: per step, issue hp LDS load FIRST, compute NEXT step's
//      zx = b + Wx*xin under its shadow (in-order issue => program position
//      is the schedule), then chain a = zx_t + Wh*hp -> cellup -> store h.
//      Accumulation order inside each dot unchanged -> identical numerics.
//      Layers 1-3: xin(t+1) ld8 from prev-layer slot before slot-t write
//      (address-disjoint; 8 thr/element are wave-lockstep, no barrier).
// ws: H1 @6291456 | W2b @40239104
typedef __attribute__((ext_vector_type(4))) float f32x4;
typedef __attribute__((ext_vector_type(16))) float f32x16;
typedef __attribute__((ext_vector_type(2))) float f32x2;
typedef __attribute__((ext_vector_type(8))) short bf16x8;

__device__ __forceinline__ ushort f2bf(float f) {
    union { float f; uint u; } v; v.f = f;
    uint u = v.u;
    return (ushort)((u + 0x7fffu + ((u >> 16) & 1u)) >> 16);   // RNE
}
__device__ __forceinline__ float sigm(float x) {
    return __builtin_amdgcn_rcpf(1.0f + __builtin_amdgcn_exp2f(x * -1.442695040888963f));
}
__device__ __forceinline__ float tanh_(float x) {
    return 2.0f * __builtin_amdgcn_rcpf(1.0f + __builtin_amdgcn_exp2f(x * -2.885390081777927f)) - 1.0f;
}
// 2xf32 -> packed 2xbf16 (RNE), gfx950 has no builtin (T12/m240)
__device__ __forceinline__ uint pk2(float a, float b) {
    uint r; asm("v_cvt_pk_bf16_f32 %0, %1, %2" : "=v"(r) : "v"(a), "v"(b)); return r;
}
__device__ __forceinline__ bf16x8 pk8(f32x4 lo, f32x4 hi) {
    union { bf16x8 v; uint u[4]; } r;
    r.u[0] = pk2(lo[0], lo[1]); r.u[1] = pk2(lo[2], lo[3]);
    r.u[2] = pk2(hi[0], hi[1]); r.u[3] = pk2(hi[2], hi[3]);
    return r.v;
}

typedef const __attribute__((address_space(1))) unsigned int ga_u32;
typedef __attribute__((address_space(3))) unsigned int lds_u32;
__device__ __forceinline__ void g2l16(const void* g, void* l) {
    __builtin_amdgcn_global_load_lds((ga_u32*)(unsigned long long)g,
                                     (lds_u32*)(unsigned int)(unsigned long long)l,
                                     16, 0, 0);
}

// ---------------------------------------------------------------- LSTM ----
struct LstmW {
    const float* wih[4];
    const float* whh[4];
    const float* bih[4];
    const float* bhh[4];
};

__device__ __forceinline__ void gates8p(const f32x2 w01[8], const f32x2 w23[8],
                                        const float xv8[8], f32x2& a01, f32x2& a23) {
#pragma unroll
    for (int k = 0; k < 8; ++k) {
        f32x2 xv = {xv8[k], xv8[k]};
        a01 += w01[k] * xv;
        a23 += w23[k] * xv;
    }
}
__device__ __forceinline__ void cellup(f32x2 a01, f32x2 a23, float& h, float& c) {
    c = sigm(a01.y) * c + sigm(a01.x) * tanh_(a23.x);
    h = sigm(a23.y) * tanh_(c);
}
__device__ __forceinline__ void ld8(const float* p, float v[8]) {
    float4 a = *(const float4*)p;
    float4 b = *(const float4*)(p + 4);
    v[0] = a.x; v[1] = a.y; v[2] = a.z; v[3] = a.w;
    v[4] = b.x; v[5] = b.y; v[6] = b.z; v[7] = b.w;
}

// blocks [0,512): LSTM + fused dense1; blocks [512,1024): W2 cvt + out init
__global__ __launch_bounds__(256) void pre_kernel(const float* __restrict__ x, LstmW p,
                                                  const float* __restrict__ W1,
                                                  const float* __restrict__ b1,
                                                  const float* __restrict__ W2,
                                                  ushort* __restrict__ W2b,
                                                  const float* __restrict__ b3,
                                                  float* __restrict__ out,
                                                  ushort* __restrict__ H1) {
    const int tid = threadIdx.x;
    if (blockIdx.x >= 512) {
        const int tg = (blockIdx.x - 512) * 256 + tid;     // 0..131071
        if (tg < 16384) {
            float4 bv = {b3[0], b3[1], b3[2], b3[3]};
            ((float4*)out)[tg] = bv;
        }
#pragma unroll
        for (int s = 0; s < 4; ++s) {
            int i = tg + s * 131072;                       // 524288 float4 of W2
            float4 v = ((const float4*)W2)[i];
            ushort4 r; r.x = f2bf(v.x); r.y = f2bf(v.y); r.z = f2bf(v.z); r.w = f2bf(v.w);
            ((ushort4*)W2b)[i] = r;
        }
        return;
    }

    __shared__ float hb[32 * 200];

    const int e0 = blockIdx.x * 32;
    const int el = tid >> 3, j = tid & 7;
    float* hr = hb + el * 200;
    const float* xg = x + (size_t)(e0 + el) * 168;

    f32x2 wx01[8], wx23[8], wh01[8], wh23[8], b01, b23;

    // ---- layer 0 (in = 7), x from global, zx pipelined ----
    {
        const float* Wih = p.wih[0];
        const float* Whh = p.whh[0];
#pragma unroll
        for (int k = 0; k < 7; ++k) {
            wx01[k] = {Wih[(0 + j) * 7 + k], Wih[(8 + j) * 7 + k]};
            wx23[k] = {Wih[(16 + j) * 7 + k], Wih[(24 + j) * 7 + k]};
        }
#pragma unroll
        for (int k = 0; k < 8; ++k) {
            wh01[k] = {Whh[(0 + j) * 8 + k], Whh[(8 + j) * 8 + k]};
            wh23[k] = {Whh[(16 + j) * 8 + k], Whh[(24 + j) * 8 + k]};
        }
        b01 = {p.bih[0][j] + p.bhh[0][j], p.bih[0][8 + j] + p.bhh[0][8 + j]};
        b23 = {p.bih[0][16 + j] + p.bhh[0][16 + j], p.bih[0][24 + j] + p.bhh[0][24 + j]};

        float h = 0.f, c = 0.f;
        // zx for t=0
        f32x2 zx01 = b01, zx23 = b23;
        {
            float xn[7];
#pragma unroll
            for (int k = 0; k < 7; ++k) xn[k] = xg[k];
#pragma unroll
            for (int k = 0; k < 7; ++k) {
                f32x2 xv = {xn[k], xn[k]};
                zx01 += wx01[k] * xv; zx23 += wx23[k] * xv;
            }
        }
        for (int t = 0; t < 24; ++t) {
            float hp[8];
            if (t > 0) ld8(&hr[(t - 1) * 8], hp);          // chain load: issue first
            // next step's zx under the hp shadow
            const int tn = (t < 23) ? t + 1 : 23;
            f32x2 nz01 = b01, nz23 = b23;
            {
                float xm[7];
#pragma unroll
                for (int k = 0; k < 7; ++k) xm[k] = xg[tn * 7 + k];
#pragma unroll
                for (int k = 0; k < 7; ++k) {
                    f32x2 xv = {xm[k], xm[k]};
                    nz01 += wx01[k] * xv; nz23 += wx23[k] * xv;
                }
            }
            f32x2 a01 = zx01, a23 = zx23;
            if (t > 0) gates8p(wh01, wh23, hp, a01, a23);
            cellup(a01, a23, h, c);
            hr[t * 8 + j] = h;
            zx01 = nz01; zx23 = nz23;
        }
    }

    // ---- layers 1..3 (in-place ping through hr), zx pipelined ----
#pragma unroll
    for (int l = 1; l < 4; ++l) {
        const float* Wih = p.wih[l];
        const float* Whh = p.whh[l];
#pragma unroll
        for (int k = 0; k < 8; ++k) {
            wx01[k] = {Wih[(0 + j) * 8 + k], Wih[(8 + j) * 8 + k]};
            wx23[k] = {Wih[(16 + j) * 8 + k], Wih[(24 + j) * 8 + k]};
            wh01[k] = {Whh[(0 + j) * 8 + k], Whh[(8 + j) * 8 + k]};
            wh23[k] = {Whh[(16 + j) * 8 + k], Whh[(24 + j) * 8 + k]};
        }
        b01 = {p.bih[l][j] + p.bhh[l][j], p.bih[l][8 + j] + p.bhh[l][8 + j]};
        b23 = {p.bih[l][16 + j] + p.bhh[l][16 + j], p.bih[l][24 + j] + p.bhh[l][24 + j]};

        float h = 0.f, c = 0.f;
        f32x2 zx01 = b01, zx23 = b23;
        {
            float xn[8]; ld8(&hr[0], xn);                  // prev layer h_0
            gates8p(wx01, wx23, xn, zx01, zx23);
        }
        for (int t = 0; t < 24; ++t) {
            float hp[8];
            if (t > 0) ld8(&hr[(t - 1) * 8], hp);          // own h (overwritten slot)
            // next xin: prev-layer slot t+1, read BEFORE slot-t write (disjoint)
            const int tn = (t < 23) ? t + 1 : 23;
            float xm[8]; ld8(&hr[tn * 8], xm);
            f32x2 nz01 = b01, nz23 = b23;
            gates8p(wx01, wx23, xm, nz01, nz23);
            f32x2 a01 = zx01, a23 = zx23;
            if (t > 0) gates8p(wh01, wh23, hp, a01, a23);
            cellup(a01, a23, h, c);
            hr[t * 8 + j] = h;
            zx01 = nz01; zx23 = nz23;
        }
    }

    // ---- fused dense1: H1[e0..e0+32,:] = relu(hb @ W1^T + b1) ----
    // hb rows (32) = Y rows; cols t*8+j (192 = K). mfma_16x16x32_bf16:
    // lane l15 = row/col index, kq = lane>>4 in 0..3 -> k = ks*32 + kq*8.
    __syncthreads();
    {
        const int lane = tid & 63;
        const int wv = tid >> 6;              // wave: n-range wv*256
        const int l15 = lane & 15, kq = lane >> 4;
        const int nw0 = wv * 256;

        bf16x8 abf[2][6];
#pragma unroll
        for (int mf = 0; mf < 2; ++mf)
#pragma unroll
            for (int ks = 0; ks < 6; ++ks) {
                const float* ap = hb + (mf * 16 + l15) * 200 + ks * 32 + kq * 8;
                f32x4 lo = *(const f32x4*)ap;
                f32x4 hi = *(const f32x4*)(ap + 4);
                abf[mf][ks] = pk8(lo, hi);
            }
#pragma unroll
        for (int nf = 0; nf < 16; ++nf) {
            const int col = nw0 + nf * 16 + l15;
            const float* wrow = W1 + (size_t)col * 192;
            bf16x8 bbf[6];
#pragma unroll
            for (int ks = 0; ks < 6; ++ks) {
                f32x4 lo = *(const f32x4*)(wrow + ks * 32 + kq * 8);
                f32x4 hi = *(const f32x4*)(wrow + ks * 32 + kq * 8 + 4);
                bbf[ks] = pk8(lo, hi);
            }
            f32x4 a0 = {0.f, 0.f, 0.f, 0.f}, a1 = {0.f, 0.f, 0.f, 0.f};
#pragma unroll
            for (int ks = 0; ks < 6; ++ks) {
                a0 = __builtin_amdgcn_mfma_f32_16x16x32_bf16(abf[0][ks], bbf[ks], a0, 0, 0, 0);
                a1 = __builtin_amdgcn_mfma_f32_16x16x32_bf16(abf[1][ks], bbf[ks], a1, 0, 0, 0);
            }
            const float bv = b1[col];
#pragma unroll
            for (int r = 0; r < 4; ++r) {
                H1[(size_t)(e0 + kq * 4 + r) * 1024 + col]      = f2bf(fmaxf(a0[r] + bv, 0.f));
                H1[(size_t)(e0 + 16 + kq * 4 + r) * 1024 + col] = f2bf(fmaxf(a1[r] + bv, 0.f));
            }
        }
    }
}

// ---------------------------------------------- gemm2: 256^2 8-phase -----
template <int OFFB>
__device__ __forceinline__ bf16x8 dsr(unsigned a) {
    bf16x8 r;
    asm volatile("ds_read_b128 %0, %1 offset:%2"
                 : "=v"(r) : "v"(a), "i"(OFFB));
    return r;
}
// one 8-MFMA sub-cluster: quad (QA,QB), k-slice KS
template <int QA, int QB, int KS>
__device__ __forceinline__ void mma_sub(f32x4 acc[8][4], const bf16x8 afr[8],
                                        const bf16x8 br[4]) {
#pragma unroll
    for (int mi = 0; mi < 4; ++mi)
#pragma unroll
        for (int ni = 0; ni < 2; ++ni)
            acc[QA * 4 + mi][QB * 2 + ni] = __builtin_amdgcn_mfma_f32_16x16x32_bf16(
                afr[mi * 2 + KS], br[ni * 2 + KS], acc[QA * 4 + mi][QB * 2 + ni],
                0, 0, 0);
}

#define SBAR()  __builtin_amdgcn_s_barrier()
#define SCHED0() __builtin_amdgcn_sched_barrier(0)
#define LGKM(N) do { asm volatile("s_waitcnt lgkmcnt(" #N ")"); SCHED0(); } while (0)
#define VMC(N)  do { asm volatile("s_waitcnt vmcnt(" #N ")" ::: "memory"); } while (0)
#define PRIO1() __builtin_amdgcn_s_setprio(1)
#define PRIO0() do { __builtin_amdgcn_s_setprio(0); SCHED0(); } while (0)

__global__ __launch_bounds__(512) void gemm2_kernel(const ushort* __restrict__ A,
                                                    const ushort* __restrict__ W,
                                                    const float* __restrict__ bias,
                                                    const float* __restrict__ W3,
                                                    float* __restrict__ outf) {
    // LDS: 2 K-tile double buffer, [256 rows][64 k] bf16 per tensor per buf.
    // A0 @0, B0 @32768, A1 @65536, B1 @98304 (byte offsets). 128 KiB.
    __shared__ alignas(16) ushort smem[65536];
    __shared__ alignas(16) float w3s[1040];   // W3[4][256] at pitch 260

    const int tid = threadIdx.x;
    // bijective XCD swizzle (512 % 8 == 0)
    const int wg = ((int)blockIdx.x & 7) * 64 + ((int)blockIdx.x >> 3);
    const int m0 = (wg >> 3) << 8;
    const int n0 = (wg & 7) << 8;

    const int lane = tid & 63;
    const int wv = tid >> 6;

    // ---- staging addressing (pre-swizzled global source, linear LDS dest)
    const int lrow = tid >> 3;                         // 0..63 rows per call
    const int lc8 = ((tid & 7) ^ (lrow & 7)) << 3;     // swizzled k-chunk
    const ushort* Ag = A + (size_t)(m0 + lrow) * 1024 + lc8;
    const ushort* Bg = W + (size_t)(n0 + lrow) * 1024 + lc8;
    ushort* const sA0 = smem;
    ushort* const sB0 = smem + 16384;
    ushort* const sA1 = smem + 32768;
    ushort* const sB1 = smem + 49152;
    const int srow64 = (wv << 3) * 64;                 // wave's LDS row base

    // ---- frag addressing: phys chunk = logical ^ (row&7); byte addrs
    const int l15 = lane & 15, kq = lane >> 4, r7 = l15 & 7;
    const int wM = wv >> 2, wN = wv & 3;               // 2M x 4N waves
    const unsigned sbase = (unsigned)(unsigned long long)&smem[0];
    const unsigned pc0B = (unsigned)((kq ^ r7) << 4);
    const unsigned pc1B = pc0B ^ 64u;                  // chunk ^= 4 (ks=1)
    const unsigned aRowB = (unsigned)((wM * 128 + l15) * 128);
    const unsigned bRowB = (unsigned)((wN * 64 + l15) * 128);
    const unsigned aA0p0 = sbase + aRowB + pc0B;
    const unsigned aA0p1 = sbase + aRowB + pc1B;
    const unsigned aA1p0 = aA0p0 + 65536u;
    const unsigned aA1p1 = aA0p1 + 65536u;
    const unsigned bB0p0 = sbase + 32768u + bRowB + pc0B;
    const unsigned bB0p1 = sbase + 32768u + bRowB + pc1B;
    const unsigned bB1p0 = bB0p0 + 65536u;
    const unsigned bB1p1 = bB0p1 + 65536u;

    auto stA = [&](int buf, int h, int kt) {           // stage A half-tile
        ushort* b = buf ? sA1 : sA0;
#pragma unroll
        for (int c = 0; c < 2; ++c)
            g2l16(Ag + (size_t)(h * 128 + c * 64) * 1024 + kt * 64,
                  b + (h * 128 + c * 64) * 64 + srow64);
    };
    auto stB = [&](int buf, int h, int kt) {           // stage B half-tile
        ushort* b = buf ? sB1 : sB0;
#pragma unroll
        for (int c = 0; c < 2; ++c)
            g2l16(Bg + (size_t)(h * 128 + c * 64) * 1024 + kt * 64,
                  b + (h * 128 + c * 64) * 64 + srow64);
    };

    f32x4 acc[8][4];
#pragma unroll
    for (int i = 0; i < 8; ++i)
#pragma unroll
        for (int j = 0; j < 4; ++j)
#pragma unroll
            for (int r = 0; r < 4; ++r) acc[i][j][r] = 0.f;

    // W3 -> LDS + bias -> regs (before staging; lgkmcnt(0) drains ds_writes)
#pragma unroll
    for (int i = 0; i < 2; ++i) {
        int idx = tid + i * 512;
        w3s[(idx >> 8) * 260 + (idx & 255)] = W3[(size_t)(idx >> 8) * 2048 + n0 + (idx & 255)];
    }
    float bias4[4];
#pragma unroll
    for (int ni = 0; ni < 4; ++ni) bias4[ni] = bias[n0 + wN * 64 + ni * 16 + l15];

    // prologue: buf0 kt0 full (8) + buf1 kt1 B both halves + A h0 (6).
    // A1h1(kt1) comes from it0's P1 stage. VMC(6) lands buf0, leaves buf1's 6.
    stA(0, 0, 0); stA(0, 1, 0); stB(0, 0, 0); stB(0, 1, 0);
    stB(1, 0, 1); stB(1, 1, 1); stA(1, 0, 1);
    asm volatile("s_waitcnt lgkmcnt(0)");              // w3s ds_writes drained
    VMC(6);
    SBAR(); SCHED0();

    bf16x8 afr[8], b0r[4], b1r[4];
    // P1s0 preload: aLo-ks0 + b0-ks0 (6 reads)
    afr[0] = dsr<0>(aA0p0);    afr[2] = dsr<2048>(aA0p0);
    afr[4] = dsr<4096>(aA0p0); afr[6] = dsr<6144>(aA0p0);
    b0r[0] = dsr<0>(bB0p0);    b0r[2] = dsr<2048>(bB0p0);

#pragma unroll 1
    for (int it = 0; it < 8; ++it) {
        const int k1 = 2 * it + 1, k2 = 2 * it + 2, k3 = 2 * it + 3;
        const bool nl = (it < 7);
        // ---- P1: quad(0,0) buf0 (aLo+b0) | stage A1h1(k1) ----
        SBAR(); SCHED0();
        afr[1] = dsr<0>(aA0p1);    afr[3] = dsr<2048>(aA0p1);
        afr[5] = dsr<4096>(aA0p1); afr[7] = dsr<6144>(aA0p1);
        b0r[1] = dsr<0>(bB0p1);    b0r[3] = dsr<2048>(bB0p1);
        stA(1, 1, k1);
        LGKM(6); PRIO1(); mma_sub<0, 0, 0>(acc, afr, b0r); PRIO0();
        b1r[0] = dsr<4096>(bB0p0); b1r[2] = dsr<6144>(bB0p0);
        LGKM(2); PRIO1(); mma_sub<0, 0, 1>(acc, afr, b0r); PRIO0();
        // ---- P2: quad(0,1) buf0 (aLo+b1) ----
        SBAR(); SCHED0();
        b1r[1] = dsr<4096>(bB0p1); b1r[3] = dsr<6144>(bB0p1);
        LGKM(2); PRIO1(); mma_sub<0, 1, 0>(acc, afr, b1r); PRIO0();
        afr[0] = dsr<8192>(aA0p0);  afr[2] = dsr<10240>(aA0p0);
        afr[4] = dsr<12288>(aA0p0); afr[6] = dsr<14336>(aA0p0);
        LGKM(4); PRIO1(); mma_sub<0, 1, 1>(acc, afr, b1r); PRIO0();
        // ---- P3: quad(1,1) buf0 (aHi+b1) | stage B0h0(k2) ----
        SBAR(); SCHED0();
        afr[1] = dsr<8192>(aA0p1);  afr[3] = dsr<10240>(aA0p1);
        afr[5] = dsr<12288>(aA0p1); afr[7] = dsr<14336>(aA0p1);
        if (nl) stB(0, 0, k2);
        LGKM(4); PRIO1(); mma_sub<1, 1, 0>(acc, afr, b1r); PRIO0();
        LGKM(0); PRIO1(); mma_sub<1, 1, 1>(acc, afr, b1r); PRIO0();
        // ---- P4: quad(1,0) buf0 (aHi+b0) | wait buf1 | stage B0h1+A0h0(k2) ----
        if (nl) { VMC(2); } else { VMC(0); }
        SBAR(); SCHED0();
        if (nl) { stB(0, 1, k2); stA(0, 0, k2); }
        PRIO1(); mma_sub<1, 0, 0>(acc, afr, b0r); PRIO0();
        afr[0] = dsr<8192>(aA1p0);  afr[2] = dsr<10240>(aA1p0);
        afr[4] = dsr<12288>(aA1p0); afr[6] = dsr<14336>(aA1p0);
        b0r[0] = dsr<0>(bB1p0);     b0r[2] = dsr<2048>(bB1p0);
        PRIO1(); mma_sub<1, 0, 1>(acc, afr, b0r); PRIO0();
        // ---- P5: quad(1,0) buf1 (aHi1+b0_1) | stage A0h1(k2) ----
        SBAR(); SCHED0();
        afr[1] = dsr<8192>(aA1p1);  afr[3] = dsr<10240>(aA1p1);
        afr[5] = dsr<12288>(aA1p1); afr[7] = dsr<14336>(aA1p1);
        b0r[1] = dsr<0>(bB1p1);     b0r[3] = dsr<2048>(bB1p1);
        if (nl) stA(0, 1, k2);
        LGKM(6); PRIO1(); mma_sub<1, 0, 0>(acc, afr, b0r); PRIO0();
        b1r[0] = dsr<4096>(bB1p0); b1r[2] = dsr<6144>(bB1p0);
        LGKM(2); PRIO1(); mma_sub<1, 0, 1>(acc, afr, b0r); PRIO0();
        // ---- P6: quad(1,1) buf1 ----
        SBAR(); SCHED0();
        b1r[1] = dsr<4096>(bB1p1); b1r[3] = dsr<6144>(bB1p1);
        LGKM(2); PRIO1(); mma_sub<1, 1, 0>(acc, afr, b1r); PRIO0();
        afr[0] = dsr<0>(aA1p0);    afr[2] = dsr<2048>(aA1p0);
        afr[4] = dsr<4096>(aA1p0); afr[6] = dsr<6144>(aA1p0);
        LGKM(4); PRIO1(); mma_sub<1, 1, 1>(acc, afr, b1r); PRIO0();
        // ---- P7: quad(0,1) buf1 (aLo1+b1_1) | stage B1h0(k3) ----
        SBAR(); SCHED0();
        afr[1] = dsr<0>(aA1p1);    afr[3] = dsr<2048>(aA1p1);
        afr[5] = dsr<4096>(aA1p1); afr[7] = dsr<6144>(aA1p1);
        if (nl) stB(1, 0, k3);
        LGKM(4); PRIO1(); mma_sub<0, 1, 0>(acc, afr, b1r); PRIO0();
        LGKM(0); PRIO1(); mma_sub<0, 1, 1>(acc, afr, b1r); PRIO0();
        // ---- P8: quad(0,0) buf1 (aLo1+b0_1) | wait buf0-k2 | stage B1h1+A1h0(k3) ----
        if (nl) { VMC(2); }
        SBAR(); SCHED0();
        if (nl) { stB(1, 1, k3); stA(1, 0, k3); }
        PRIO1(); mma_sub<0, 0, 0>(acc, afr, b0r); PRIO0();
        if (nl) {   // P1s0 of next iter (buf0, k2)
            afr[0] = dsr<0>(aA0p0);    afr[2] = dsr<2048>(aA0p0);
            afr[4] = dsr<4096>(aA0p0); afr[6] = dsr<6144>(aA0p0);
            b0r[0] = dsr<0>(bB0p0);    b0r[2] = dsr<2048>(bB0p0);
        }
        PRIO1(); mma_sub<0, 0, 1>(acc, afr, b0r); PRIO0();
    }

    // ---- fused relu + W3 epilogue: 4 slab passes over Cs[64][260] f32 ----
    // De-broadcast dot: lane j8 owns cols {j8*4 + 32k, k=0..7} (disjoint,
    // bank = 4*drow + 4*j8 -> conflict-free). One Cs read serves 4 outputs.
    float* Cs = (float*)smem;
    const int drow = tid >> 3;            // 0..63
    const int j8 = tid & 7;               // col-interleave lane
    __syncthreads();
#pragma unroll
    for (int s = 0; s < 4; ++s) {
        if (wM == (s >> 1)) {
            const int mb = (s & 1) * 4;
#pragma unroll
            for (int mi = 0; mi < 4; ++mi)
#pragma unroll
                for (int ni = 0; ni < 4; ++ni) {
                    f32x4 v = acc[mb + mi][ni];
                    const int cbase = (mi * 16 + kq * 4) * 260 + wN * 64 + ni * 16 + l15;
#pragma unroll
                    for (int r = 0; r < 4; ++r)
                        Cs[cbase + r * 260] = fmaxf(v[r] + bias4[ni], 0.f);
                }
        }
        __syncthreads();
        {
            const float* crow = &Cs[drow * 260 + j8 * 4];
            f32x4 pp = {0.f, 0.f, 0.f, 0.f};
#pragma unroll
            for (int k = 0; k < 8; ++k) {
                f32x4 cv = *(const f32x4*)(crow + k * 32);
#pragma unroll
                for (int q = 0; q < 4; ++q) {
                    f32x4 wv4 = *(const f32x4*)(&w3s[q * 260 + j8 * 4 + k * 32]);
                    pp[q] += cv[0] * wv4[0] + cv[1] * wv4[1] + cv[2] * wv4[2] + cv[3] * wv4[3];
                }
            }
#pragma unroll
            for (int m = 1; m < 8; m <<= 1) {
#pragma unroll
                for (int q = 0; q < 4; ++q) pp[q] += __shfl_xor(pp[q], m);
            }
            const float pv = (j8 == 0) ? pp[0] : (j8 == 1) ? pp[1]
                           : (j8 == 2) ? pp[2] : pp[3];
            if (j8 < 4)
                atomicAdd(&outf[(size_t)(m0 + s * 64 + drow) * 4 + j8], pv);
        }
        __syncthreads();
    }
}

// -------------------------------------------------------------- launch ----
extern "C" void kernel_launch(void* const* d_in, const int* in_sizes, int n_in,
                              void* d_out, int out_size, void* d_ws, size_t ws_size,
                              hipStream_t stream) {
    const float* x = (const float*)d_in[0];
    LstmW w;
    for (int l = 0; l < 4; ++l) {
        w.wih[l] = (const float*)d_in[1 + 4 * l];
        w.whh[l] = (const float*)d_in[2 + 4 * l];
        w.bih[l] = (const float*)d_in[3 + 4 * l];
        w.bhh[l] = (const float*)d_in[4 + 4 * l];
    }
    const float* Wd1 = (const float*)d_in[17];
    const float* bd1 = (const float*)d_in[18];
    const float* Wd2 = (const float*)d_in[19];
    const float* bd2 = (const float*)d_in[20];
    const float* Wd3 = (const float*)d_in[21];
    const float* bd3 = (const float*)d_in[22];
    float* out = (float*)d_out;

    ushort* H1  = (ushort*)((char*)d_ws + 6291456);
    ushort* W2b = (ushort*)((char*)d_ws + 40239104);

    pre_kernel<<<1024, 256, 0, stream>>>(x, w, Wd1, bd1, Wd2, W2b, bd3, out, H1);
    gemm2_kernel<<<512, 512, 0, stream>>>(H1, W2b, bd2, Wd3, out);
}

// Round 10
// 222.938 us; speedup vs baseline: 1.0410x; 1.0410x over previous
//
#include <hip/hip_runtime.h>
#include <hip/hip_bf16.h>

// LSTM_80960133529703: B=16384, T=24, F=7, H=8, L=4; dense 192->1024->2048->4.
// R18: REVERT to R12 (session champion, 205.6us) + one zero-risk change:
//      #pragma unroll on the LSTM's inner t-loops (layer 0 and layers 1-3).
//      Full unroll -> static hr offsets -> compiler may hoist step t+1's
//      h-independent loads (xin/x) above step t's transcendental tail.
//      Same per-step FP order -> identical numerics. All sync structure,
//      gemm1, gemm2, launch config byte-identical to R12.
// ws: Y @0 | H1 @6291456 | W1b @39845888 | W2b @40239104
typedef __attribute__((ext_vector_type(4))) float f32x4;
typedef __attribute__((ext_vector_type(16))) float f32x16;
typedef __attribute__((ext_vector_type(2))) float f32x2;
typedef __attribute__((ext_vector_type(8))) short bf16x8;

__device__ __forceinline__ ushort f2bf(float f) {
    union { float f; uint u; } v; v.f = f;
    uint u = v.u;
    return (ushort)((u + 0x7fffu + ((u >> 16) & 1u)) >> 16);   // RNE
}
__device__ __forceinline__ float sigm(float x) {
    return __builtin_amdgcn_rcpf(1.0f + __builtin_amdgcn_exp2f(x * -1.442695040888963f));
}
__device__ __forceinline__ float tanh_(float x) {
    return 2.0f * __builtin_amdgcn_rcpf(1.0f + __builtin_amdgcn_exp2f(x * -2.885390081777927f)) - 1.0f;
}

typedef const __attribute__((address_space(1))) unsigned int ga_u32;
typedef __attribute__((address_space(3))) unsigned int lds_u32;
__device__ __forceinline__ void g2l16(const void* g, void* l) {
    __builtin_amdgcn_global_load_lds((ga_u32*)(unsigned long long)g,
                                     (lds_u32*)(unsigned int)(unsigned long long)l,
                                     16, 0, 0);
}

// ---------------------------------------------------------------- LSTM ----
struct LstmW {
    const float* wih[4];
    const float* whh[4];
    const float* bih[4];
    const float* bhh[4];
};

__device__ __forceinline__ void gates8p(const f32x2 w01[8], const f32x2 w23[8],
                                        const float xv8[8], f32x2& a01, f32x2& a23) {
#pragma unroll
    for (int k = 0; k < 8; ++k) {
        f32x2 xv = {xv8[k], xv8[k]};
        a01 += w01[k] * xv;
        a23 += w23[k] * xv;
    }
}
__device__ __forceinline__ void cellup(f32x2 a01, f32x2 a23, float& h, float& c) {
    c = sigm(a01.y) * c + sigm(a01.x) * tanh_(a23.x);
    h = sigm(a23.y) * tanh_(c);
}
__device__ __forceinline__ void ld8(const float* p, float v[8]) {
    float4 a = *(const float4*)p;
    float4 b = *(const float4*)(p + 4);
    v[0] = a.x; v[1] = a.y; v[2] = a.z; v[3] = a.w;
    v[4] = b.x; v[5] = b.y; v[6] = b.z; v[7] = b.w;
}

// blocks [0,512): LSTM; blocks [512, 512+560): weight cvt fp32->bf16 (+ out init)
__global__ __launch_bounds__(256) void pre_kernel(const float* __restrict__ x, LstmW p,
                                                  ushort* __restrict__ Y,
                                                  const float* __restrict__ W1,
                                                  const float* __restrict__ W2,
                                                  ushort* __restrict__ W1b,
                                                  ushort* __restrict__ W2b,
                                                  const float* __restrict__ b3,
                                                  float* __restrict__ out) {
    __shared__ float xs[32 * 168];
    __shared__ float hb[32 * 200];

    const int tid = threadIdx.x;
    if (blockIdx.x >= 512) {
        const int tg = (blockIdx.x - 512) * 256 + tid;
        if (tg < 16384) {
            float4 bv = {b3[0], b3[1], b3[2], b3[3]};
            ((float4*)out)[tg] = bv;
        }
#pragma unroll
        for (int s = 0; s < 4; ++s) {
            int i = tg + s * 143360;
            const float4* src; ushort4* dst; int off;
            if (i < 49152) { src = (const float4*)W1; dst = (ushort4*)W1b; off = i; }
            else { src = (const float4*)W2; dst = (ushort4*)W2b; off = i - 49152; }
            float4 v = src[off];
            ushort4 r; r.x = f2bf(v.x); r.y = f2bf(v.y); r.z = f2bf(v.z); r.w = f2bf(v.w);
            dst[off] = r;
        }
        return;
    }

    const int e0 = blockIdx.x * 32;
    {
        const float4* s = (const float4*)(x + (size_t)e0 * 168);
        float4* d = (float4*)xs;
        for (int i = tid; i < 1344; i += 256) d[i] = s[i];
    }
    __syncthreads();

    const int el = tid >> 3, j = tid & 7;
    float* hr = hb + el * 200;
    const float* xr = xs + el * 168;

    f32x2 wx01[8], wx23[8], wh01[8], wh23[8], b01, b23;

    // ---- layer 0 (in = 7) ----
    {
        const float* Wih = p.wih[0];
        const float* Whh = p.whh[0];
#pragma unroll
        for (int k = 0; k < 7; ++k) {
            wx01[k] = {Wih[(0 + j) * 7 + k], Wih[(8 + j) * 7 + k]};
            wx23[k] = {Wih[(16 + j) * 7 + k], Wih[(24 + j) * 7 + k]};
        }
#pragma unroll
        for (int k = 0; k < 8; ++k) {
            wh01[k] = {Whh[(0 + j) * 8 + k], Whh[(8 + j) * 8 + k]};
            wh23[k] = {Whh[(16 + j) * 8 + k], Whh[(24 + j) * 8 + k]};
        }
        b01 = {p.bih[0][j] + p.bhh[0][j], p.bih[0][8 + j] + p.bhh[0][8 + j]};
        b23 = {p.bih[0][16 + j] + p.bhh[0][16 + j], p.bih[0][24 + j] + p.bhh[0][24 + j]};

        float h = 0.f, c = 0.f;
        {
            f32x2 a01 = b01, a23 = b23;
#pragma unroll
            for (int k = 0; k < 7; ++k) {
                f32x2 xv = {xr[k], xr[k]};
                a01 += wx01[k] * xv; a23 += wx23[k] * xv;
            }
            cellup(a01, a23, h, c);
            hr[j] = h;
        }
#pragma unroll
        for (int t = 1; t < 24; ++t) {
            f32x2 a01 = b01, a23 = b23;
#pragma unroll
            for (int k = 0; k < 7; ++k) {
                f32x2 xv = {xr[t * 7 + k], xr[t * 7 + k]};
                a01 += wx01[k] * xv; a23 += wx23[k] * xv;
            }
            float hp[8]; ld8(&hr[(t - 1) * 8], hp);
            gates8p(wh01, wh23, hp, a01, a23);
            cellup(a01, a23, h, c);
            hr[t * 8 + j] = h;
        }
    }

    // ---- layers 1..3 ----
#pragma unroll
    for (int l = 1; l < 4; ++l) {
        const float* Wih = p.wih[l];
        const float* Whh = p.whh[l];
#pragma unroll
        for (int k = 0; k < 8; ++k) {
            wx01[k] = {Wih[(0 + j) * 8 + k], Wih[(8 + j) * 8 + k]};
            wx23[k] = {Wih[(16 + j) * 8 + k], Wih[(24 + j) * 8 + k]};
            wh01[k] = {Whh[(0 + j) * 8 + k], Whh[(8 + j) * 8 + k]};
            wh23[k] = {Whh[(16 + j) * 8 + k], Whh[(24 + j) * 8 + k]};
        }
        b01 = {p.bih[l][j] + p.bhh[l][j], p.bih[l][8 + j] + p.bhh[l][8 + j]};
        b23 = {p.bih[l][16 + j] + p.bhh[l][16 + j], p.bih[l][24 + j] + p.bhh[l][24 + j]};

        float h = 0.f, c = 0.f;
        {
            float xin[8]; ld8(&hr[0], xin);
            f32x2 a01 = b01, a23 = b23;
            gates8p(wx01, wx23, xin, a01, a23);
            cellup(a01, a23, h, c);
            hr[j] = h;
            if (l == 3) Y[((size_t)(e0 + el) * 24) * 8 + j] = f2bf(h);
        }
#pragma unroll
        for (int t = 1; t < 24; ++t) {
            float xin[8]; ld8(&hr[t * 8], xin);   // h-independent: issues early
            float hp[8];  ld8(&hr[(t - 1) * 8], hp);
            f32x2 a01 = b01, a23 = b23;
            gates8p(wx01, wx23, xin, a01, a23);
            gates8p(wh01, wh23, hp, a01, a23);
            cellup(a01, a23, h, c);
            hr[t * 8 + j] = h;
            if (l == 3) Y[((size_t)(e0 + el) * 24 + t) * 8 + j] = f2bf(h);
        }
    }
}

// ------------------------------------------------------- gemm1 (K=192) ----
// Tile 128x128, BK=64, 4 waves; wave tile 64x64 as 2x2 of mfma_32x32x16.
template <int KDIM>
__device__ __forceinline__ void gemm_body(const ushort* __restrict__ A,
                                          const ushort* __restrict__ W,
                                          const float* __restrict__ bias,
                                          ushort* __restrict__ Hout, int N) {
    __shared__ alignas(16) ushort smem[16384];
    ushort* As = smem;            // [128][64] swizzled
    ushort* Ws = smem + 8192;

    const int tid = threadIdx.x;
    const int m0 = blockIdx.x * 128;
    const int n0 = blockIdx.y * 128;
    const int lane = tid & 63;
    const int wv = tid >> 6;
    const int wm = (wv & 1) * 64;
    const int wn = (wv >> 1) * 64;
    const int l31 = lane & 31;
    const int kh = lane >> 5;

    // staging: per wave, 4 calls/tensor; call c: rows wv*32 + c*8 + lrow
    const int lrow = lane >> 3;
    const int lchunk = (lane & 7) ^ lrow;          // XOR swizzle at source
    const ushort* Ag = A + (size_t)(m0 + wv * 32 + lrow) * KDIM + lchunk * 8;
    const ushort* Wg = W + (size_t)(n0 + wv * 32 + lrow) * KDIM + lchunk * 8;
    ushort* Ald = As + wv * 2048;
    ushort* Wld = Ws + wv * 2048;

    const int r7 = l31 & 7;
    const int arow0 = (wm + l31) * 64;        // mi=0; mi=1 adds 32*64
    const int brow0 = (wn + l31) * 64;

    f32x16 acc[2][2];
#pragma unroll
    for (int mi = 0; mi < 2; ++mi)
#pragma unroll
        for (int ni = 0; ni < 2; ++ni)
#pragma unroll
            for (int r = 0; r < 16; ++r) acc[mi][ni][r] = 0.f;

    for (int k0 = 0; k0 < KDIM; k0 += 64) {
#pragma unroll
        for (int c = 0; c < 4; ++c)
            g2l16(Ag + (size_t)c * 8 * KDIM + k0, Ald + c * 512);
#pragma unroll
        for (int c = 0; c < 4; ++c)
            g2l16(Wg + (size_t)c * 8 * KDIM + k0, Wld + c * 512);
        __syncthreads();

#pragma unroll
        for (int ks = 0; ks < 4; ++ks) {
            const int ck = ((ks * 2 + kh) ^ r7) * 8;
            bf16x8 afr[2], bfr[2];
#pragma unroll
            for (int mi = 0; mi < 2; ++mi)
                afr[mi] = *(const bf16x8*)&As[arow0 + mi * 2048 + ck];
#pragma unroll
            for (int ni = 0; ni < 2; ++ni)
                bfr[ni] = *(const bf16x8*)&Ws[brow0 + ni * 2048 + ck];
#pragma unroll
            for (int mi = 0; mi < 2; ++mi)
#pragma unroll
                for (int ni = 0; ni < 2; ++ni)
                    acc[mi][ni] = __builtin_amdgcn_mfma_f32_32x32x16_bf16(afr[mi], bfr[ni],
                                                                         acc[mi][ni], 0, 0, 0);
        }
        __syncthreads();
    }

#pragma unroll
    for (int ni = 0; ni < 2; ++ni) {
        const int col = n0 + wn + ni * 32 + l31;
        const float b = bias[col];
#pragma unroll
        for (int mi = 0; mi < 2; ++mi)
#pragma unroll
            for (int r = 0; r < 16; ++r) {
                const int row = m0 + wm + mi * 32 + (r & 3) + 8 * (r >> 2) + 4 * kh;
                Hout[(size_t)row * N + col] = f2bf(fmaxf(acc[mi][ni][r] + b, 0.f));
            }
    }
}

__global__ __launch_bounds__(256, 4) void gemm1_kernel(const ushort* __restrict__ A,
                                                       const ushort* __restrict__ W,
                                                       const float* __restrict__ bias,
                                                       ushort* __restrict__ Hout, int N) {
    gemm_body<192>(A, W, bias, Hout, N);
}

// ---------------------------------------------- gemm2: 256^2 8-phase -----
template <int OFFB>
__device__ __forceinline__ bf16x8 dsr(unsigned a) {
    bf16x8 r;
    asm volatile("ds_read_b128 %0, %1 offset:%2"
                 : "=v"(r) : "v"(a), "i"(OFFB));
    return r;
}
// one 8-MFMA sub-cluster: quad (QA,QB), k-slice KS
template <int QA, int QB, int KS>
__device__ __forceinline__ void mma_sub(f32x4 acc[8][4], const bf16x8 afr[8],
                                        const bf16x8 br[4]) {
#pragma unroll
    for (int mi = 0; mi < 4; ++mi)
#pragma unroll
        for (int ni = 0; ni < 2; ++ni)
            acc[QA * 4 + mi][QB * 2 + ni] = __builtin_amdgcn_mfma_f32_16x16x32_bf16(
                afr[mi * 2 + KS], br[ni * 2 + KS], acc[QA * 4 + mi][QB * 2 + ni],
                0, 0, 0);
}

#define SBAR()  __builtin_amdgcn_s_barrier()
#define SCHED0() __builtin_amdgcn_sched_barrier(0)
#define LGKM(N) do { asm volatile("s_waitcnt lgkmcnt(" #N ")"); SCHED0(); } while (0)
#define VMC(N)  do { asm volatile("s_waitcnt vmcnt(" #N ")" ::: "memory"); } while (0)
#define PRIO1() __builtin_amdgcn_s_setprio(1)
#define PRIO0() do { __builtin_amdgcn_s_setprio(0); SCHED0(); } while (0)

__global__ __launch_bounds__(512) void gemm2_kernel(const ushort* __restrict__ A,
                                                    const ushort* __restrict__ W,
                                                    const float* __restrict__ bias,
                                                    const float* __restrict__ W3,
                                                    float* __restrict__ outf) {
    // LDS: 2 K-tile double buffer, [256 rows][64 k] bf16 per tensor per buf.
    // A0 @0, B0 @32768, A1 @65536, B1 @98304 (byte offsets). 128 KiB.
    __shared__ alignas(16) ushort smem[65536];
    __shared__ alignas(16) float w3s[1040];   // W3[4][256] at pitch 260

    const int tid = threadIdx.x;
    // bijective XCD swizzle (512 % 8 == 0)
    const int wg = ((int)blockIdx.x & 7) * 64 + ((int)blockIdx.x >> 3);
    const int m0 = (wg >> 3) << 8;
    const int n0 = (wg & 7) << 8;

    const int lane = tid & 63;
    const int wv = tid >> 6;

    // ---- staging addressing (pre-swizzled global source, linear LDS dest)
    const int lrow = tid >> 3;                         // 0..63 rows per call
    const int lc8 = ((tid & 7) ^ (lrow & 7)) << 3;     // swizzled k-chunk
    const ushort* Ag = A + (size_t)(m0 + lrow) * 1024 + lc8;
    const ushort* Bg = W + (size_t)(n0 + lrow) * 1024 + lc8;
    ushort* const sA0 = smem;
    ushort* const sB0 = smem + 16384;
    ushort* const sA1 = smem + 32768;
    ushort* const sB1 = smem + 49152;
    const int srow64 = (wv << 3) * 64;                 // wave's LDS row base

    // ---- frag addressing: phys chunk = logical ^ (row&7); byte addrs
    const int l15 = lane & 15, kq = lane >> 4, r7 = l15 & 7;
    const int wM = wv >> 2, wN = wv & 3;               // 2M x 4N waves
    const unsigned sbase = (unsigned)(unsigned long long)&smem[0];
    const unsigned pc0B = (unsigned)((kq ^ r7) << 4);
    const unsigned pc1B = pc0B ^ 64u;                  // chunk ^= 4 (ks=1)
    const unsigned aRowB = (unsigned)((wM * 128 + l15) * 128);
    const unsigned bRowB = (unsigned)((wN * 64 + l15) * 128);
    const unsigned aA0p0 = sbase + aRowB + pc0B;
    const unsigned aA0p1 = sbase + aRowB + pc1B;
    const unsigned aA1p0 = aA0p0 + 65536u;
    const unsigned aA1p1 = aA0p1 + 65536u;
    const unsigned bB0p0 = sbase + 32768u + bRowB + pc0B;
    const unsigned bB0p1 = sbase + 32768u + bRowB + pc1B;
    const unsigned bB1p0 = bB0p0 + 65536u;
    const unsigned bB1p1 = bB0p1 + 65536u;

    auto stA = [&](int buf, int h, int kt) {           // stage A half-tile
        ushort* b = buf ? sA1 : sA0;
#pragma unroll
        for (int c = 0; c < 2; ++c)
            g2l16(Ag + (size_t)(h * 128 + c * 64) * 1024 + kt * 64,
                  b + (h * 128 + c * 64) * 64 + srow64);
    };
    auto stB = [&](int buf, int h, int kt) {           // stage B half-tile
        ushort* b = buf ? sB1 : sB0;
#pragma unroll
        for (int c = 0; c < 2; ++c)
            g2l16(Bg + (size_t)(h * 128 + c * 64) * 1024 + kt * 64,
                  b + (h * 128 + c * 64) * 64 + srow64);
    };

    f32x4 acc[8][4];
#pragma unroll
    for (int i = 0; i < 8; ++i)
#pragma unroll
        for (int j = 0; j < 4; ++j)
#pragma unroll
            for (int r = 0; r < 4; ++r) acc[i][j][r] = 0.f;

    // W3 -> LDS + bias -> regs (before staging; lgkmcnt(0) drains ds_writes)
#pragma unroll
    for (int i = 0; i < 2; ++i) {
        int idx = tid + i * 512;
        w3s[(idx >> 8) * 260 + (idx & 255)] = W3[(size_t)(idx >> 8) * 2048 + n0 + (idx & 255)];
    }
    float bias4[4];
#pragma unroll
    for (int ni = 0; ni < 4; ++ni) bias4[ni] = bias[n0 + wN * 64 + ni * 16 + l15];

    // prologue: buf0 kt0 full (8) + buf1 kt1 B both halves + A h0 (6).
    // A1h1(kt1) comes from it0's P1 stage. VMC(6) lands buf0, leaves buf1's 6.
    stA(0, 0, 0); stA(0, 1, 0); stB(0, 0, 0); stB(0, 1, 0);
    stB(1, 0, 1); stB(1, 1, 1); stA(1, 0, 1);
    asm volatile("s_waitcnt lgkmcnt(0)");              // w3s ds_writes drained
    VMC(6);
    SBAR(); SCHED0();

    bf16x8 afr[8], b0r[4], b1r[4];
    // P1s0 preload: aLo-ks0 + b0-ks0 (6 reads)
    afr[0] = dsr<0>(aA0p0);    afr[2] = dsr<2048>(aA0p0);
    afr[4] = dsr<4096>(aA0p0); afr[6] = dsr<6144>(aA0p0);
    b0r[0] = dsr<0>(bB0p0);    b0r[2] = dsr<2048>(bB0p0);

#pragma unroll 1
    for (int it = 0; it < 8; ++it) {
        const int k1 = 2 * it + 1, k2 = 2 * it + 2, k3 = 2 * it + 3;
        const bool nl = (it < 7);
        // ---- P1: quad(0,0) buf0 (aLo+b0) | stage A1h1(k1) ----
        SBAR(); SCHED0();
        afr[1] = dsr<0>(aA0p1);    afr[3] = dsr<2048>(aA0p1);
        afr[5] = dsr<4096>(aA0p1); afr[7] = dsr<6144>(aA0p1);
        b0r[1] = dsr<0>(bB0p1);    b0r[3] = dsr<2048>(bB0p1);
        stA(1, 1, k1);
        LGKM(6); PRIO1(); mma_sub<0, 0, 0>(acc, afr, b0r); PRIO0();
        b1r[0] = dsr<4096>(bB0p0); b1r[2] = dsr<6144>(bB0p0);
        LGKM(2); PRIO1(); mma_sub<0, 0, 1>(acc, afr, b0r); PRIO0();
        // ---- P2: quad(0,1) buf0 (aLo+b1) ----
        SBAR(); SCHED0();
        b1r[1] = dsr<4096>(bB0p1); b1r[3] = dsr<6144>(bB0p1);
        LGKM(2); PRIO1(); mma_sub<0, 1, 0>(acc, afr, b1r); PRIO0();
        afr[0] = dsr<8192>(aA0p0);  afr[2] = dsr<10240>(aA0p0);
        afr[4] = dsr<12288>(aA0p0); afr[6] = dsr<14336>(aA0p0);
        LGKM(4); PRIO1(); mma_sub<0, 1, 1>(acc, afr, b1r); PRIO0();
        // ---- P3: quad(1,1) buf0 (aHi+b1) | stage B0h0(k2) ----
        SBAR(); SCHED0();
        afr[1] = dsr<8192>(aA0p1);  afr[3] = dsr<10240>(aA0p1);
        afr[5] = dsr<12288>(aA0p1); afr[7] = dsr<14336>(aA0p1);
        if (nl) stB(0, 0, k2);
        LGKM(4); PRIO1(); mma_sub<1, 1, 0>(acc, afr, b1r); PRIO0();
        LGKM(0); PRIO1(); mma_sub<1, 1, 1>(acc, afr, b1r); PRIO0();
        // ---- P4: quad(1,0) buf0 (aHi+b0) | wait buf1 | stage B0h1+A0h0(k2) ----
        if (nl) { VMC(2); } else { VMC(0); }
        SBAR(); SCHED0();
        if (nl) { stB(0, 1, k2); stA(0, 0, k2); }
        PRIO1(); mma_sub<1, 0, 0>(acc, afr, b0r); PRIO0();
        afr[0] = dsr<8192>(aA1p0);  afr[2] = dsr<10240>(aA1p0);
        afr[4] = dsr<12288>(aA1p0); afr[6] = dsr<14336>(aA1p0);
        b0r[0] = dsr<0>(bB1p0);     b0r[2] = dsr<2048>(bB1p0);
        PRIO1(); mma_sub<1, 0, 1>(acc, afr, b0r); PRIO0();
        // ---- P5: quad(1,0) buf1 (aHi1+b0_1) | stage A0h1(k2) ----
        SBAR(); SCHED0();
        afr[1] = dsr<8192>(aA1p1);  afr[3] = dsr<10240>(aA1p1);
        afr[5] = dsr<12288>(aA1p1); afr[7] = dsr<14336>(aA1p1);
        b0r[1] = dsr<0>(bB1p1);     b0r[3] = dsr<2048>(bB1p1);
        if (nl) stA(0, 1, k2);
        LGKM(6); PRIO1(); mma_sub<1, 0, 0>(acc, afr, b0r); PRIO0();
        b1r[0] = dsr<4096>(bB1p0); b1r[2] = dsr<6144>(bB1p0);
        LGKM(2); PRIO1(); mma_sub<1, 0, 1>(acc, afr, b0r); PRIO0();
        // ---- P6: quad(1,1) buf1 ----
        SBAR(); SCHED0();
        b1r[1] = dsr<4096>(bB1p1); b1r[3] = dsr<6144>(bB1p1);
        LGKM(2); PRIO1(); mma_sub<1, 1, 0>(acc, afr, b1r); PRIO0();
        afr[0] = dsr<0>(aA1p0);    afr[2] = dsr<2048>(aA1p0);
        afr[4] = dsr<4096>(aA1p0); afr[6] = dsr<6144>(aA1p0);
        LGKM(4); PRIO1(); mma_sub<1, 1, 1>(acc, afr, b1r); PRIO0();
        // ---- P7: quad(0,1) buf1 (aLo1+b1_1) | stage B1h0(k3) ----
        SBAR(); SCHED0();
        afr[1] = dsr<0>(aA1p1);    afr[3] = dsr<2048>(aA1p1);
        afr[5] = dsr<4096>(aA1p1); afr[7] = dsr<6144>(aA1p1);
        if (nl) stB(1, 0, k3);
        LGKM(4); PRIO1(); mma_sub<0, 1, 0>(acc, afr, b1r); PRIO0();
        LGKM(0); PRIO1(); mma_sub<0, 1, 1>(acc, afr, b1r); PRIO0();
        // ---- P8: quad(0,0) buf1 (aLo1+b0_1) | wait buf0-k2 | stage B1h1+A1h0(k3) ----
        if (nl) { VMC(2); }
        SBAR(); SCHED0();
        if (nl) { stB(1, 1, k3); stA(1, 0, k3); }
        PRIO1(); mma_sub<0, 0, 0>(acc, afr, b0r); PRIO0();
        if (nl) {   // P1s0 of next iter (buf0, k2)
            afr[0] = dsr<0>(aA0p0);    afr[2] = dsr<2048>(aA0p0);
            afr[4] = dsr<4096>(aA0p0); afr[6] = dsr<6144>(aA0p0);
            b0r[0] = dsr<0>(bB0p0);    b0r[2] = dsr<2048>(bB0p0);
        }
        PRIO1(); mma_sub<0, 0, 1>(acc, afr, b0r); PRIO0();
    }

    // ---- fused relu + W3 epilogue: 4 slab passes over Cs[64][260] f32 ----
    // De-broadcast dot: lane j8 owns cols {j8*4 + 32k, k=0..7} (disjoint,
    // bank = 4*drow + 4*j8 -> conflict-free). One Cs read serves 4 outputs.
    float* Cs = (float*)smem;
    const int drow = tid >> 3;            // 0..63
    const int j8 = tid & 7;               // col-interleave lane
    __syncthreads();
#pragma unroll
    for (int s = 0; s < 4; ++s) {
        if (wM == (s >> 1)) {
            const int mb = (s & 1) * 4;
#pragma unroll
            for (int mi = 0; mi < 4; ++mi)
#pragma unroll
                for (int ni = 0; ni < 4; ++ni) {
                    f32x4 v = acc[mb + mi][ni];
                    const int cbase = (mi * 16 + kq * 4) * 260 + wN * 64 + ni * 16 + l15;
#pragma unroll
                    for (int r = 0; r < 4; ++r)
                        Cs[cbase + r * 260] = fmaxf(v[r] + bias4[ni], 0.f);
                }
        }
        __syncthreads();
        {
            const float* crow = &Cs[drow * 260 + j8 * 4];
            f32x4 pp = {0.f, 0.f, 0.f, 0.f};
#pragma unroll
            for (int k = 0; k < 8; ++k) {
                f32x4 cv = *(const f32x4*)(crow + k * 32);
#pragma unroll
                for (int q = 0; q < 4; ++q) {
                    f32x4 wv4 = *(const f32x4*)(&w3s[q * 260 + j8 * 4 + k * 32]);
                    pp[q] += cv[0] * wv4[0] + cv[1] * wv4[1] + cv[2] * wv4[2] + cv[3] * wv4[3];
                }
            }
#pragma unroll
            for (int m = 1; m < 8; m <<= 1) {
#pragma unroll
                for (int q = 0; q < 4; ++q) pp[q] += __shfl_xor(pp[q], m);
            }
            const float pv = (j8 == 0) ? pp[0] : (j8 == 1) ? pp[1]
                           : (j8 == 2) ? pp[2] : pp[3];
            if (j8 < 4)
                atomicAdd(&outf[(size_t)(m0 + s * 64 + drow) * 4 + j8], pv);
        }
        __syncthreads();
    }
}

// -------------------------------------------------------------- launch ----
extern "C" void kernel_launch(void* const* d_in, const int* in_sizes, int n_in,
                              void* d_out, int out_size, void* d_ws, size_t ws_size,
                              hipStream_t stream) {
    const float* x = (const float*)d_in[0];
    LstmW w;
    for (int l = 0; l < 4; ++l) {
        w.wih[l] = (const float*)d_in[1 + 4 * l];
        w.whh[l] = (const float*)d_in[2 + 4 * l];
        w.bih[l] = (const float*)d_in[3 + 4 * l];
        w.bhh[l] = (const float*)d_in[4 + 4 * l];
    }
    const float* Wd1 = (const float*)d_in[17];
    const float* bd1 = (const float*)d_in[18];
    const float* Wd2 = (const float*)d_in[19];
    const float* bd2 = (const float*)d_in[20];
    const float* Wd3 = (const float*)d_in[21];
    const float* bd3 = (const float*)d_in[22];
    float* out = (float*)d_out;

    ushort* Y   = (ushort*)d_ws;
    ushort* H1  = (ushort*)((char*)d_ws + 6291456);
    ushort* W1b = (ushort*)((char*)d_ws + 39845888);
    ushort* W2b = (ushort*)((char*)d_ws + 40239104);

    pre_kernel<<<1072, 256, 0, stream>>>(x, w, Y, Wd1, Wd2, W1b, W2b, bd3, out);
    gemm1_kernel<<<dim3(128, 8), 256, 0, stream>>>(Y, W1b, bd1, H1, 1024);
    gemm2_kernel<<<512, 512, 0, stream>>>(H1, W2b, bd2, Wd3, out);
}

// Round 11
// 217.089 us; speedup vs baseline: 1.0690x; 1.0269x over previous
//
#include <hip/hip_runtime.h>
#include <hip/hip_bf16.h>

// LSTM_80960133529703: B=16384, T=24, F=7, H=8, L=4; dense 192->1024->2048->4.
// R19: EXACT revert to R12 (session champion, 205.6us). R18's t-loop unroll
//      regressed pre_kernel 45-55 -> 81-102us (I$ thrash: huge unrolled
//      serial body, run-to-run variance, VALUBusy 35->22%). Rolled loops
//      restored. Everything else identical to R12:
//  - pre: LSTM (512 blk, 32 elem, 8 thr/elem, LDS hr ping) + wcvt branch.
//  - gemm1: 128x128 BK=64 mfma_32x32x16, K=192.
//  - gemm2: 256^2 8-phase, half-phase-ahead lgkm pipeline, deep vmcnt
//    cover (VMC(2)@P4/P8), st_16x32-class chunk-XOR swizzle, setprio,
//    fused relu+W3 epilogue with de-broadcast dot.
// ws: Y @0 | H1 @6291456 | W1b @39845888 | W2b @40239104
typedef __attribute__((ext_vector_type(4))) float f32x4;
typedef __attribute__((ext_vector_type(16))) float f32x16;
typedef __attribute__((ext_vector_type(2))) float f32x2;
typedef __attribute__((ext_vector_type(8))) short bf16x8;

__device__ __forceinline__ ushort f2bf(float f) {
    union { float f; uint u; } v; v.f = f;
    uint u = v.u;
    return (ushort)((u + 0x7fffu + ((u >> 16) & 1u)) >> 16);   // RNE
}
__device__ __forceinline__ float sigm(float x) {
    return __builtin_amdgcn_rcpf(1.0f + __builtin_amdgcn_exp2f(x * -1.442695040888963f));
}
__device__ __forceinline__ float tanh_(float x) {
    return 2.0f * __builtin_amdgcn_rcpf(1.0f + __builtin_amdgcn_exp2f(x * -2.885390081777927f)) - 1.0f;
}

typedef const __attribute__((address_space(1))) unsigned int ga_u32;
typedef __attribute__((address_space(3))) unsigned int lds_u32;
__device__ __forceinline__ void g2l16(const void* g, void* l) {
    __builtin_amdgcn_global_load_lds((ga_u32*)(unsigned long long)g,
                                     (lds_u32*)(unsigned int)(unsigned long long)l,
                                     16, 0, 0);
}

// ---------------------------------------------------------------- LSTM ----
struct LstmW {
    const float* wih[4];
    const float* whh[4];
    const float* bih[4];
    const float* bhh[4];
};

__device__ __forceinline__ void gates8p(const f32x2 w01[8], const f32x2 w23[8],
                                        const float xv8[8], f32x2& a01, f32x2& a23) {
#pragma unroll
    for (int k = 0; k < 8; ++k) {
        f32x2 xv = {xv8[k], xv8[k]};
        a01 += w01[k] * xv;
        a23 += w23[k] * xv;
    }
}
__device__ __forceinline__ void cellup(f32x2 a01, f32x2 a23, float& h, float& c) {
    c = sigm(a01.y) * c + sigm(a01.x) * tanh_(a23.x);
    h = sigm(a23.y) * tanh_(c);
}
__device__ __forceinline__ void ld8(const float* p, float v[8]) {
    float4 a = *(const float4*)p;
    float4 b = *(const float4*)(p + 4);
    v[0] = a.x; v[1] = a.y; v[2] = a.z; v[3] = a.w;
    v[4] = b.x; v[5] = b.y; v[6] = b.z; v[7] = b.w;
}

// blocks [0,512): LSTM; blocks [512, 512+560): weight cvt fp32->bf16 (+ out init)
__global__ __launch_bounds__(256) void pre_kernel(const float* __restrict__ x, LstmW p,
                                                  ushort* __restrict__ Y,
                                                  const float* __restrict__ W1,
                                                  const float* __restrict__ W2,
                                                  ushort* __restrict__ W1b,
                                                  ushort* __restrict__ W2b,
                                                  const float* __restrict__ b3,
                                                  float* __restrict__ out) {
    __shared__ float xs[32 * 168];
    __shared__ float hb[32 * 200];

    const int tid = threadIdx.x;
    if (blockIdx.x >= 512) {
        const int tg = (blockIdx.x - 512) * 256 + tid;
        if (tg < 16384) {
            float4 bv = {b3[0], b3[1], b3[2], b3[3]};
            ((float4*)out)[tg] = bv;
        }
#pragma unroll
        for (int s = 0; s < 4; ++s) {
            int i = tg + s * 143360;
            const float4* src; ushort4* dst; int off;
            if (i < 49152) { src = (const float4*)W1; dst = (ushort4*)W1b; off = i; }
            else { src = (const float4*)W2; dst = (ushort4*)W2b; off = i - 49152; }
            float4 v = src[off];
            ushort4 r; r.x = f2bf(v.x); r.y = f2bf(v.y); r.z = f2bf(v.z); r.w = f2bf(v.w);
            dst[off] = r;
        }
        return;
    }

    const int e0 = blockIdx.x * 32;
    {
        const float4* s = (const float4*)(x + (size_t)e0 * 168);
        float4* d = (float4*)xs;
        for (int i = tid; i < 1344; i += 256) d[i] = s[i];
    }
    __syncthreads();

    const int el = tid >> 3, j = tid & 7;
    float* hr = hb + el * 200;
    const float* xr = xs + el * 168;

    f32x2 wx01[8], wx23[8], wh01[8], wh23[8], b01, b23;

    // ---- layer 0 (in = 7) ----
    {
        const float* Wih = p.wih[0];
        const float* Whh = p.whh[0];
#pragma unroll
        for (int k = 0; k < 7; ++k) {
            wx01[k] = {Wih[(0 + j) * 7 + k], Wih[(8 + j) * 7 + k]};
            wx23[k] = {Wih[(16 + j) * 7 + k], Wih[(24 + j) * 7 + k]};
        }
#pragma unroll
        for (int k = 0; k < 8; ++k) {
            wh01[k] = {Whh[(0 + j) * 8 + k], Whh[(8 + j) * 8 + k]};
            wh23[k] = {Whh[(16 + j) * 8 + k], Whh[(24 + j) * 8 + k]};
        }
        b01 = {p.bih[0][j] + p.bhh[0][j], p.bih[0][8 + j] + p.bhh[0][8 + j]};
        b23 = {p.bih[0][16 + j] + p.bhh[0][16 + j], p.bih[0][24 + j] + p.bhh[0][24 + j]};

        float h = 0.f, c = 0.f;
        {
            f32x2 a01 = b01, a23 = b23;
#pragma unroll
            for (int k = 0; k < 7; ++k) {
                f32x2 xv = {xr[k], xr[k]};
                a01 += wx01[k] * xv; a23 += wx23[k] * xv;
            }
            cellup(a01, a23, h, c);
            hr[j] = h;
        }
        for (int t = 1; t < 24; ++t) {
            f32x2 a01 = b01, a23 = b23;
#pragma unroll
            for (int k = 0; k < 7; ++k) {
                f32x2 xv = {xr[t * 7 + k], xr[t * 7 + k]};
                a01 += wx01[k] * xv; a23 += wx23[k] * xv;
            }
            float hp[8]; ld8(&hr[(t - 1) * 8], hp);
            gates8p(wh01, wh23, hp, a01, a23);
            cellup(a01, a23, h, c);
            hr[t * 8 + j] = h;
        }
    }

    // ---- layers 1..3 ----
#pragma unroll
    for (int l = 1; l < 4; ++l) {
        const float* Wih = p.wih[l];
        const float* Whh = p.whh[l];
#pragma unroll
        for (int k = 0; k < 8; ++k) {
            wx01[k] = {Wih[(0 + j) * 8 + k], Wih[(8 + j) * 8 + k]};
            wx23[k] = {Wih[(16 + j) * 8 + k], Wih[(24 + j) * 8 + k]};
            wh01[k] = {Whh[(0 + j) * 8 + k], Whh[(8 + j) * 8 + k]};
            wh23[k] = {Whh[(16 + j) * 8 + k], Whh[(24 + j) * 8 + k]};
        }
        b01 = {p.bih[l][j] + p.bhh[l][j], p.bih[l][8 + j] + p.bhh[l][8 + j]};
        b23 = {p.bih[l][16 + j] + p.bhh[l][16 + j], p.bih[l][24 + j] + p.bhh[l][24 + j]};

        float h = 0.f, c = 0.f;
        {
            float xin[8]; ld8(&hr[0], xin);
            f32x2 a01 = b01, a23 = b23;
            gates8p(wx01, wx23, xin, a01, a23);
            cellup(a01, a23, h, c);
            hr[j] = h;
            if (l == 3) Y[((size_t)(e0 + el) * 24) * 8 + j] = f2bf(h);
        }
        for (int t = 1; t < 24; ++t) {
            float xin[8]; ld8(&hr[t * 8], xin);
            float hp[8];  ld8(&hr[(t - 1) * 8], hp);
            f32x2 a01 = b01, a23 = b23;
            gates8p(wx01, wx23, xin, a01, a23);
            gates8p(wh01, wh23, hp, a01, a23);
            cellup(a01, a23, h, c);
            hr[t * 8 + j] = h;
            if (l == 3) Y[((size_t)(e0 + el) * 24 + t) * 8 + j] = f2bf(h);
        }
    }
}

// ------------------------------------------------------- gemm1 (K=192) ----
// Tile 128x128, BK=64, 4 waves; wave tile 64x64 as 2x2 of mfma_32x32x16.
template <int KDIM>
__device__ __forceinline__ void gemm_body(const ushort* __restrict__ A,
                                          const ushort* __restrict__ W,
                                          const float* __restrict__ bias,
                                          ushort* __restrict__ Hout, int N) {
    __shared__ alignas(16) ushort smem[16384];
    ushort* As = smem;            // [128][64] swizzled
    ushort* Ws = smem + 8192;

    const int tid = threadIdx.x;
    const int m0 = blockIdx.x * 128;
    const int n0 = blockIdx.y * 128;
    const int lane = tid & 63;
    const int wv = tid >> 6;
    const int wm = (wv & 1) * 64;
    const int wn = (wv >> 1) * 64;
    const int l31 = lane & 31;
    const int kh = lane >> 5;

    // staging: per wave, 4 calls/tensor; call c: rows wv*32 + c*8 + lrow
    const int lrow = lane >> 3;
    const int lchunk = (lane & 7) ^ lrow;          // XOR swizzle at source
    const ushort* Ag = A + (size_t)(m0 + wv * 32 + lrow) * KDIM + lchunk * 8;
    const ushort* Wg = W + (size_t)(n0 + wv * 32 + lrow) * KDIM + lchunk * 8;
    ushort* Ald = As + wv * 2048;
    ushort* Wld = Ws + wv * 2048;

    const int r7 = l31 & 7;
    const int arow0 = (wm + l31) * 64;        // mi=0; mi=1 adds 32*64
    const int brow0 = (wn + l31) * 64;

    f32x16 acc[2][2];
#pragma unroll
    for (int mi = 0; mi < 2; ++mi)
#pragma unroll
        for (int ni = 0; ni < 2; ++ni)
#pragma unroll
            for (int r = 0; r < 16; ++r) acc[mi][ni][r] = 0.f;

    for (int k0 = 0; k0 < KDIM; k0 += 64) {
#pragma unroll
        for (int c = 0; c < 4; ++c)
            g2l16(Ag + (size_t)c * 8 * KDIM + k0, Ald + c * 512);
#pragma unroll
        for (int c = 0; c < 4; ++c)
            g2l16(Wg + (size_t)c * 8 * KDIM + k0, Wld + c * 512);
        __syncthreads();

#pragma unroll
        for (int ks = 0; ks < 4; ++ks) {
            const int ck = ((ks * 2 + kh) ^ r7) * 8;
            bf16x8 afr[2], bfr[2];
#pragma unroll
            for (int mi = 0; mi < 2; ++mi)
                afr[mi] = *(const bf16x8*)&As[arow0 + mi * 2048 + ck];
#pragma unroll
            for (int ni = 0; ni < 2; ++ni)
                bfr[ni] = *(const bf16x8*)&Ws[brow0 + ni * 2048 + ck];
#pragma unroll
            for (int mi = 0; mi < 2; ++mi)
#pragma unroll
                for (int ni = 0; ni < 2; ++ni)
                    acc[mi][ni] = __builtin_amdgcn_mfma_f32_32x32x16_bf16(afr[mi], bfr[ni],
                                                                         acc[mi][ni], 0, 0, 0);
        }
        __syncthreads();
    }

#pragma unroll
    for (int ni = 0; ni < 2; ++ni) {
        const int col = n0 + wn + ni * 32 + l31;
        const float b = bias[col];
#pragma unroll
        for (int mi = 0; mi < 2; ++mi)
#pragma unroll
            for (int r = 0; r < 16; ++r) {
                const int row = m0 + wm + mi * 32 + (r & 3) + 8 * (r >> 2) + 4 * kh;
                Hout[(size_t)row * N + col] = f2bf(fmaxf(acc[mi][ni][r] + b, 0.f));
            }
    }
}

__global__ __launch_bounds__(256, 4) void gemm1_kernel(const ushort* __restrict__ A,
                                                       const ushort* __restrict__ W,
                                                       const float* __restrict__ bias,
                                                       ushort* __restrict__ Hout, int N) {
    gemm_body<192>(A, W, bias, Hout, N);
}

// ---------------------------------------------- gemm2: 256^2 8-phase -----
template <int OFFB>
__device__ __forceinline__ bf16x8 dsr(unsigned a) {
    bf16x8 r;
    asm volatile("ds_read_b128 %0, %1 offset:%2"
                 : "=v"(r) : "v"(a), "i"(OFFB));
    return r;
}
// one 8-MFMA sub-cluster: quad (QA,QB), k-slice KS
template <int QA, int QB, int KS>
__device__ __forceinline__ void mma_sub(f32x4 acc[8][4], const bf16x8 afr[8],
                                        const bf16x8 br[4]) {
#pragma unroll
    for (int mi = 0; mi < 4; ++mi)
#pragma unroll
        for (int ni = 0; ni < 2; ++ni)
            acc[QA * 4 + mi][QB * 2 + ni] = __builtin_amdgcn_mfma_f32_16x16x32_bf16(
                afr[mi * 2 + KS], br[ni * 2 + KS], acc[QA * 4 + mi][QB * 2 + ni],
                0, 0, 0);
}

#define SBAR()  __builtin_amdgcn_s_barrier()
#define SCHED0() __builtin_amdgcn_sched_barrier(0)
#define LGKM(N) do { asm volatile("s_waitcnt lgkmcnt(" #N ")"); SCHED0(); } while (0)
#define VMC(N)  do { asm volatile("s_waitcnt vmcnt(" #N ")" ::: "memory"); } while (0)
#define PRIO1() __builtin_amdgcn_s_setprio(1)
#define PRIO0() do { __builtin_amdgcn_s_setprio(0); SCHED0(); } while (0)

__global__ __launch_bounds__(512) void gemm2_kernel(const ushort* __restrict__ A,
                                                    const ushort* __restrict__ W,
                                                    const float* __restrict__ bias,
                                                    const float* __restrict__ W3,
                                                    float* __restrict__ outf) {
    // LDS: 2 K-tile double buffer, [256 rows][64 k] bf16 per tensor per buf.
    // A0 @0, B0 @32768, A1 @65536, B1 @98304 (byte offsets). 128 KiB.
    __shared__ alignas(16) ushort smem[65536];
    __shared__ alignas(16) float w3s[1040];   // W3[4][256] at pitch 260

    const int tid = threadIdx.x;
    // bijective XCD swizzle (512 % 8 == 0)
    const int wg = ((int)blockIdx.x & 7) * 64 + ((int)blockIdx.x >> 3);
    const int m0 = (wg >> 3) << 8;
    const int n0 = (wg & 7) << 8;

    const int lane = tid & 63;
    const int wv = tid >> 6;

    // ---- staging addressing (pre-swizzled global source, linear LDS dest)
    const int lrow = tid >> 3;                         // 0..63 rows per call
    const int lc8 = ((tid & 7) ^ (lrow & 7)) << 3;     // swizzled k-chunk
    const ushort* Ag = A + (size_t)(m0 + lrow) * 1024 + lc8;
    const ushort* Bg = W + (size_t)(n0 + lrow) * 1024 + lc8;
    ushort* const sA0 = smem;
    ushort* const sB0 = smem + 16384;
    ushort* const sA1 = smem + 32768;
    ushort* const sB1 = smem + 49152;
    const int srow64 = (wv << 3) * 64;                 // wave's LDS row base

    // ---- frag addressing: phys chunk = logical ^ (row&7); byte addrs
    const int l15 = lane & 15, kq = lane >> 4, r7 = l15 & 7;
    const int wM = wv >> 2, wN = wv & 3;               // 2M x 4N waves
    const unsigned sbase = (unsigned)(unsigned long long)&smem[0];
    const unsigned pc0B = (unsigned)((kq ^ r7) << 4);
    const unsigned pc1B = pc0B ^ 64u;                  // chunk ^= 4 (ks=1)
    const unsigned aRowB = (unsigned)((wM * 128 + l15) * 128);
    const unsigned bRowB = (unsigned)((wN * 64 + l15) * 128);
    const unsigned aA0p0 = sbase + aRowB + pc0B;
    const unsigned aA0p1 = sbase + aRowB + pc1B;
    const unsigned aA1p0 = aA0p0 + 65536u;
    const unsigned aA1p1 = aA0p1 + 65536u;
    const unsigned bB0p0 = sbase + 32768u + bRowB + pc0B;
    const unsigned bB0p1 = sbase + 32768u + bRowB + pc1B;
    const unsigned bB1p0 = bB0p0 + 65536u;
    const unsigned bB1p1 = bB0p1 + 65536u;

    auto stA = [&](int buf, int h, int kt) {           // stage A half-tile
        ushort* b = buf ? sA1 : sA0;
#pragma unroll
        for (int c = 0; c < 2; ++c)
            g2l16(Ag + (size_t)(h * 128 + c * 64) * 1024 + kt * 64,
                  b + (h * 128 + c * 64) * 64 + srow64);
    };
    auto stB = [&](int buf, int h, int kt) {           // stage B half-tile
        ushort* b = buf ? sB1 : sB0;
#pragma unroll
        for (int c = 0; c < 2; ++c)
            g2l16(Bg + (size_t)(h * 128 + c * 64) * 1024 + kt * 64,
                  b + (h * 128 + c * 64) * 64 + srow64);
    };

    f32x4 acc[8][4];
#pragma unroll
    for (int i = 0; i < 8; ++i)
#pragma unroll
        for (int j = 0; j < 4; ++j)
#pragma unroll
            for (int r = 0; r < 4; ++r) acc[i][j][r] = 0.f;

    // W3 -> LDS + bias -> regs (before staging; lgkmcnt(0) drains ds_writes)
#pragma unroll
    for (int i = 0; i < 2; ++i) {
        int idx = tid + i * 512;
        w3s[(idx >> 8) * 260 + (idx & 255)] = W3[(size_t)(idx >> 8) * 2048 + n0 + (idx & 255)];
    }
    float bias4[4];
#pragma unroll
    for (int ni = 0; ni < 4; ++ni) bias4[ni] = bias[n0 + wN * 64 + ni * 16 + l15];

    // prologue: buf0 kt0 full (8) + buf1 kt1 B both halves + A h0 (6).
    // A1h1(kt1) comes from it0's P1 stage. VMC(6) lands buf0, leaves buf1's 6.
    stA(0, 0, 0); stA(0, 1, 0); stB(0, 0, 0); stB(0, 1, 0);
    stB(1, 0, 1); stB(1, 1, 1); stA(1, 0, 1);
    asm volatile("s_waitcnt lgkmcnt(0)");              // w3s ds_writes drained
    VMC(6);
    SBAR(); SCHED0();

    bf16x8 afr[8], b0r[4], b1r[4];
    // P1s0 preload: aLo-ks0 + b0-ks0 (6 reads)
    afr[0] = dsr<0>(aA0p0);    afr[2] = dsr<2048>(aA0p0);
    afr[4] = dsr<4096>(aA0p0); afr[6] = dsr<6144>(aA0p0);
    b0r[0] = dsr<0>(bB0p0);    b0r[2] = dsr<2048>(bB0p0);

#pragma unroll 1
    for (int it = 0; it < 8; ++it) {
        const int k1 = 2 * it + 1, k2 = 2 * it + 2, k3 = 2 * it + 3;
        const bool nl = (it < 7);
        // ---- P1: quad(0,0) buf0 (aLo+b0) | stage A1h1(k1) ----
        SBAR(); SCHED0();
        afr[1] = dsr<0>(aA0p1);    afr[3] = dsr<2048>(aA0p1);
        afr[5] = dsr<4096>(aA0p1); afr[7] = dsr<6144>(aA0p1);
        b0r[1] = dsr<0>(bB0p1);    b0r[3] = dsr<2048>(bB0p1);
        stA(1, 1, k1);
        LGKM(6); PRIO1(); mma_sub<0, 0, 0>(acc, afr, b0r); PRIO0();
        b1r[0] = dsr<4096>(bB0p0); b1r[2] = dsr<6144>(bB0p0);
        LGKM(2); PRIO1(); mma_sub<0, 0, 1>(acc, afr, b0r); PRIO0();
        // ---- P2: quad(0,1) buf0 (aLo+b1) ----
        SBAR(); SCHED0();
        b1r[1] = dsr<4096>(bB0p1); b1r[3] = dsr<6144>(bB0p1);
        LGKM(2); PRIO1(); mma_sub<0, 1, 0>(acc, afr, b1r); PRIO0();
        afr[0] = dsr<8192>(aA0p0);  afr[2] = dsr<10240>(aA0p0);
        afr[4] = dsr<12288>(aA0p0); afr[6] = dsr<14336>(aA0p0);
        LGKM(4); PRIO1(); mma_sub<0, 1, 1>(acc, afr, b1r); PRIO0();
        // ---- P3: quad(1,1) buf0 (aHi+b1) | stage B0h0(k2) ----
        SBAR(); SCHED0();
        afr[1] = dsr<8192>(aA0p1);  afr[3] = dsr<10240>(aA0p1);
        afr[5] = dsr<12288>(aA0p1); afr[7] = dsr<14336>(aA0p1);
        if (nl) stB(0, 0, k2);
        LGKM(4); PRIO1(); mma_sub<1, 1, 0>(acc, afr, b1r); PRIO0();
        LGKM(0); PRIO1(); mma_sub<1, 1, 1>(acc, afr, b1r); PRIO0();
        // ---- P4: quad(1,0) buf0 (aHi+b0) | wait buf1 | stage B0h1+A0h0(k2) ----
        if (nl) { VMC(2); } else { VMC(0); }
        SBAR(); SCHED0();
        if (nl) { stB(0, 1, k2); stA(0, 0, k2); }
        PRIO1(); mma_sub<1, 0, 0>(acc, afr, b0r); PRIO0();
        afr[0] = dsr<8192>(aA1p0);  afr[2] = dsr<10240>(aA1p0);
        afr[4] = dsr<12288>(aA1p0); afr[6] = dsr<14336>(aA1p0);
        b0r[0] = dsr<0>(bB1p0);     b0r[2] = dsr<2048>(bB1p0);
        PRIO1(); mma_sub<1, 0, 1>(acc, afr, b0r); PRIO0();
        // ---- P5: quad(1,0) buf1 (aHi1+b0_1) | stage A0h1(k2) ----
        SBAR(); SCHED0();
        afr[1] = dsr<8192>(aA1p1);  afr[3] = dsr<10240>(aA1p1);
        afr[5] = dsr<12288>(aA1p1); afr[7] = dsr<14336>(aA1p1);
        b0r[1] = dsr<0>(bB1p1);     b0r[3] = dsr<2048>(bB1p1);
        if (nl) stA(0, 1, k2);
        LGKM(6); PRIO1(); mma_sub<1, 0, 0>(acc, afr, b0r); PRIO0();
        b1r[0] = dsr<4096>(bB1p0); b1r[2] = dsr<6144>(bB1p0);
        LGKM(2); PRIO1(); mma_sub<1, 0, 1>(acc, afr, b0r); PRIO0();
        // ---- P6: quad(1,1) buf1 ----
        SBAR(); SCHED0();
        b1r[1] = dsr<4096>(bB1p1); b1r[3] = dsr<6144>(bB1p1);
        LGKM(2); PRIO1(); mma_sub<1, 1, 0>(acc, afr, b1r); PRIO0();
        afr[0] = dsr<0>(aA1p0);    afr[2] = dsr<2048>(aA1p0);
        afr[4] = dsr<4096>(aA1p0); afr[6] = dsr<6144>(aA1p0);
        LGKM(4); PRIO1(); mma_sub<1, 1, 1>(acc, afr, b1r); PRIO0();
        // ---- P7: quad(0,1) buf1 (aLo1+b1_1) | stage B1h0(k3) ----
        SBAR(); SCHED0();
        afr[1] = dsr<0>(aA1p1);    afr[3] = dsr<2048>(aA1p1);
        afr[5] = dsr<4096>(aA1p1); afr[7] = dsr<6144>(aA1p1);
        if (nl) stB(1, 0, k3);
        LGKM(4); PRIO1(); mma_sub<0, 1, 0>(acc, afr, b1r); PRIO0();
        LGKM(0); PRIO1(); mma_sub<0, 1, 1>(acc, afr, b1r); PRIO0();
        // ---- P8: quad(0,0) buf1 (aLo1+b0_1) | wait buf0-k2 | stage B1h1+A1h0(k3) ----
        if (nl) { VMC(2); }
        SBAR(); SCHED0();
        if (nl) { stB(1, 1, k3); stA(1, 0, k3); }
        PRIO1(); mma_sub<0, 0, 0>(acc, afr, b0r); PRIO0();
        if (nl) {   // P1s0 of next iter (buf0, k2)
            afr[0] = dsr<0>(aA0p0);    afr[2] = dsr<2048>(aA0p0);
            afr[4] = dsr<4096>(aA0p0); afr[6] = dsr<6144>(aA0p0);
            b0r[0] = dsr<0>(bB0p0);    b0r[2] = dsr<2048>(bB0p0);
        }
        PRIO1(); mma_sub<0, 0, 1>(acc, afr, b0r); PRIO0();
    }

    // ---- fused relu + W3 epilogue: 4 slab passes over Cs[64][260] f32 ----
    // De-broadcast dot: lane j8 owns cols {j8*4 + 32k, k=0..7} (disjoint,
    // bank = 4*drow + 4*j8 -> conflict-free). One Cs read serves 4 outputs.
    float* Cs = (float*)smem;
    const int drow = tid >> 3;            // 0..63
    const int j8 = tid & 7;               // col-interleave lane
    __syncthreads();
#pragma unroll
    for (int s = 0; s < 4; ++s) {
        if (wM == (s >> 1)) {
            const int mb = (s & 1) * 4;
#pragma unroll
            for (int mi = 0; mi < 4; ++mi)
#pragma unroll
                for (int ni = 0; ni < 4; ++ni) {
                    f32x4 v = acc[mb + mi][ni];
                    const int cbase = (mi * 16 + kq * 4) * 260 + wN * 64 + ni * 16 + l15;
#pragma unroll
                    for (int r = 0; r < 4; ++r)
                        Cs[cbase + r * 260] = fmaxf(v[r] + bias4[ni], 0.f);
                }
        }
        __syncthreads();
        {
            const float* crow = &Cs[drow * 260 + j8 * 4];
            f32x4 pp = {0.f, 0.f, 0.f, 0.f};
#pragma unroll
            for (int k = 0; k < 8; ++k) {
                f32x4 cv = *(const f32x4*)(crow + k * 32);
#pragma unroll
                for (int q = 0; q < 4; ++q) {
                    f32x4 wv4 = *(const f32x4*)(&w3s[q * 260 + j8 * 4 + k * 32]);
                    pp[q] += cv[0] * wv4[0] + cv[1] * wv4[1] + cv[2] * wv4[2] + cv[3] * wv4[3];
                }
            }
#pragma unroll
            for (int m = 1; m < 8; m <<= 1) {
#pragma unroll
                for (int q = 0; q < 4; ++q) pp[q] += __shfl_xor(pp[q], m);
            }
            const float pv = (j8 == 0) ? pp[0] : (j8 == 1) ? pp[1]
                           : (j8 == 2) ? pp[2] : pp[3];
            if (j8 < 4)
                atomicAdd(&outf[(size_t)(m0 + s * 64 + drow) * 4 + j8], pv);
        }
        __syncthreads();
    }
}

// -------------------------------------------------------------- launch ----
extern "C" void kernel_launch(void* const* d_in, const int* in_sizes, int n_in,
                              void* d_out, int out_size, void* d_ws, size_t ws_size,
                              hipStream_t stream) {
    const float* x = (const float*)d_in[0];
    LstmW w;
    for (int l = 0; l < 4; ++l) {
        w.wih[l] = (const float*)d_in[1 + 4 * l];
        w.whh[l] = (const float*)d_in[2 + 4 * l];
        w.bih[l] = (const float*)d_in[3 + 4 * l];
        w.bhh[l] = (const float*)d_in[4 + 4 * l];
    }
    const float* Wd1 = (const float*)d_in[17];
    const float* bd1 = (const float*)d_in[18];
    const float* Wd2 = (const float*)d_in[19];
    const float* bd2 = (const float*)d_in[20];
    const float* Wd3 = (const float*)d_in[21];
    const float* bd3 = (const float*)d_in[22];
    float* out = (float*)d_out;

    ushort* Y   = (ushort*)d_ws;
    ushort* H1  = (ushort*)((char*)d_ws + 6291456);
    ushort* W1b = (ushort*)((char*)d_ws + 39845888);
    ushort* W2b = (ushort*)((char*)d_ws + 40239104);

    pre_kernel<<<1072, 256, 0, stream>>>(x, w, Y, Wd1, Wd2, W1b, W2b, bd3, out);
    gemm1_kernel<<<dim3(128, 8), 256, 0, stream>>>(Y, W1b, bd1, H1, 1024);
    gemm2_kernel<<<512, 512, 0, stream>>>(H1, W2b, bd2, Wd3, out);
}

// Round 12
// 215.699 us; speedup vs baseline: 1.0759x; 1.0064x over previous
//
#include <hip/hip_runtime.h>
#include <hip/hip_bf16.h>

// LSTM_80960133529703: B=16384, T=24, F=7, H=8, L=4; dense 192->1024->2048->4.
// R20: R19/R12 champion + ONE change: LSTM h-exchange via register shfl.
//      hp[k] = __shfl(h, base+k) (8 lanes/element are contiguous wave lanes;
//      exact same values -> bit-identical numerics). Removes the per-step
//      ds_write->ds_read round-trip (~150cy) from the 96-step serial chain;
//      replaces with an ~60cy bpermute burst. hr writes kept for layers<3
//      (next layer's xin, off-chain); layer-3 hr writes dropped (unread).
//      R13 tested this idea confounded with a kernel split (-overlap);
//      this is the clean A/B. Everything else byte-identical to R19.
// ws: Y @0 | H1 @6291456 | W1b @39845888 | W2b @40239104
typedef __attribute__((ext_vector_type(4))) float f32x4;
typedef __attribute__((ext_vector_type(16))) float f32x16;
typedef __attribute__((ext_vector_type(2))) float f32x2;
typedef __attribute__((ext_vector_type(8))) short bf16x8;

__device__ __forceinline__ ushort f2bf(float f) {
    union { float f; uint u; } v; v.f = f;
    uint u = v.u;
    return (ushort)((u + 0x7fffu + ((u >> 16) & 1u)) >> 16);   // RNE
}
__device__ __forceinline__ float sigm(float x) {
    return __builtin_amdgcn_rcpf(1.0f + __builtin_amdgcn_exp2f(x * -1.442695040888963f));
}
__device__ __forceinline__ float tanh_(float x) {
    return 2.0f * __builtin_amdgcn_rcpf(1.0f + __builtin_amdgcn_exp2f(x * -2.885390081777927f)) - 1.0f;
}

typedef const __attribute__((address_space(1))) unsigned int ga_u32;
typedef __attribute__((address_space(3))) unsigned int lds_u32;
__device__ __forceinline__ void g2l16(const void* g, void* l) {
    __builtin_amdgcn_global_load_lds((ga_u32*)(unsigned long long)g,
                                     (lds_u32*)(unsigned int)(unsigned long long)l,
                                     16, 0, 0);
}

// ---------------------------------------------------------------- LSTM ----
struct LstmW {
    const float* wih[4];
    const float* whh[4];
    const float* bih[4];
    const float* bhh[4];
};

__device__ __forceinline__ void gates8p(const f32x2 w01[8], const f32x2 w23[8],
                                        const float xv8[8], f32x2& a01, f32x2& a23) {
#pragma unroll
    for (int k = 0; k < 8; ++k) {
        f32x2 xv = {xv8[k], xv8[k]};
        a01 += w01[k] * xv;
        a23 += w23[k] * xv;
    }
}
__device__ __forceinline__ void cellup(f32x2 a01, f32x2 a23, float& h, float& c) {
    c = sigm(a01.y) * c + sigm(a01.x) * tanh_(a23.x);
    h = sigm(a23.y) * tanh_(c);
}
__device__ __forceinline__ void ld8(const float* p, float v[8]) {
    float4 a = *(const float4*)p;
    float4 b = *(const float4*)(p + 4);
    v[0] = a.x; v[1] = a.y; v[2] = a.z; v[3] = a.w;
    v[4] = b.x; v[5] = b.y; v[6] = b.z; v[7] = b.w;
}
// hp[k] = h of lane (lane&~7)+k within this wave (register gather, exact)
__device__ __forceinline__ void hshfl(float h, float hp[8]) {
    const int base = ((int)threadIdx.x & 63) & ~7;
#pragma unroll
    for (int k = 0; k < 8; ++k) hp[k] = __shfl(h, base + k, 64);
}

// blocks [0,512): LSTM; blocks [512, 512+560): weight cvt fp32->bf16 (+ out init)
__global__ __launch_bounds__(256) void pre_kernel(const float* __restrict__ x, LstmW p,
                                                  ushort* __restrict__ Y,
                                                  const float* __restrict__ W1,
                                                  const float* __restrict__ W2,
                                                  ushort* __restrict__ W1b,
                                                  ushort* __restrict__ W2b,
                                                  const float* __restrict__ b3,
                                                  float* __restrict__ out) {
    __shared__ float xs[32 * 168];
    __shared__ float hb[32 * 200];

    const int tid = threadIdx.x;
    if (blockIdx.x >= 512) {
        const int tg = (blockIdx.x - 512) * 256 + tid;
        if (tg < 16384) {
            float4 bv = {b3[0], b3[1], b3[2], b3[3]};
            ((float4*)out)[tg] = bv;
        }
#pragma unroll
        for (int s = 0; s < 4; ++s) {
            int i = tg + s * 143360;
            const float4* src; ushort4* dst; int off;
            if (i < 49152) { src = (const float4*)W1; dst = (ushort4*)W1b; off = i; }
            else { src = (const float4*)W2; dst = (ushort4*)W2b; off = i - 49152; }
            float4 v = src[off];
            ushort4 r; r.x = f2bf(v.x); r.y = f2bf(v.y); r.z = f2bf(v.z); r.w = f2bf(v.w);
            dst[off] = r;
        }
        return;
    }

    const int e0 = blockIdx.x * 32;
    {
        const float4* s = (const float4*)(x + (size_t)e0 * 168);
        float4* d = (float4*)xs;
        for (int i = tid; i < 1344; i += 256) d[i] = s[i];
    }
    __syncthreads();

    const int el = tid >> 3, j = tid & 7;
    float* hr = hb + el * 200;
    const float* xr = xs + el * 168;

    f32x2 wx01[8], wx23[8], wh01[8], wh23[8], b01, b23;

    // ---- layer 0 (in = 7) ----
    {
        const float* Wih = p.wih[0];
        const float* Whh = p.whh[0];
#pragma unroll
        for (int k = 0; k < 7; ++k) {
            wx01[k] = {Wih[(0 + j) * 7 + k], Wih[(8 + j) * 7 + k]};
            wx23[k] = {Wih[(16 + j) * 7 + k], Wih[(24 + j) * 7 + k]};
        }
#pragma unroll
        for (int k = 0; k < 8; ++k) {
            wh01[k] = {Whh[(0 + j) * 8 + k], Whh[(8 + j) * 8 + k]};
            wh23[k] = {Whh[(16 + j) * 8 + k], Whh[(24 + j) * 8 + k]};
        }
        b01 = {p.bih[0][j] + p.bhh[0][j], p.bih[0][8 + j] + p.bhh[0][8 + j]};
        b23 = {p.bih[0][16 + j] + p.bhh[0][16 + j], p.bih[0][24 + j] + p.bhh[0][24 + j]};

        float h = 0.f, c = 0.f;
        {
            f32x2 a01 = b01, a23 = b23;
#pragma unroll
            for (int k = 0; k < 7; ++k) {
                f32x2 xv = {xr[k], xr[k]};
                a01 += wx01[k] * xv; a23 += wx23[k] * xv;
            }
            cellup(a01, a23, h, c);
            hr[j] = h;
        }
        for (int t = 1; t < 24; ++t) {
            f32x2 a01 = b01, a23 = b23;
#pragma unroll
            for (int k = 0; k < 7; ++k) {
                f32x2 xv = {xr[t * 7 + k], xr[t * 7 + k]};
                a01 += wx01[k] * xv; a23 += wx23[k] * xv;
            }
            float hp[8]; hshfl(h, hp);            // register gather (was ld8 hr)
            gates8p(wh01, wh23, hp, a01, a23);
            cellup(a01, a23, h, c);
            hr[t * 8 + j] = h;                    // needed by layer 1 xin
        }
    }

    // ---- layers 1..3 ----
#pragma unroll
    for (int l = 1; l < 4; ++l) {
        const float* Wih = p.wih[l];
        const float* Whh = p.whh[l];
#pragma unroll
        for (int k = 0; k < 8; ++k) {
            wx01[k] = {Wih[(0 + j) * 8 + k], Wih[(8 + j) * 8 + k]};
            wx23[k] = {Wih[(16 + j) * 8 + k], Wih[(24 + j) * 8 + k]};
            wh01[k] = {Whh[(0 + j) * 8 + k], Whh[(8 + j) * 8 + k]};
            wh23[k] = {Whh[(16 + j) * 8 + k], Whh[(24 + j) * 8 + k]};
        }
        b01 = {p.bih[l][j] + p.bhh[l][j], p.bih[l][8 + j] + p.bhh[l][8 + j]};
        b23 = {p.bih[l][16 + j] + p.bhh[l][16 + j], p.bih[l][24 + j] + p.bhh[l][24 + j]};

        float h = 0.f, c = 0.f;
        {
            float xin[8]; ld8(&hr[0], xin);
            f32x2 a01 = b01, a23 = b23;
            gates8p(wx01, wx23, xin, a01, a23);
            cellup(a01, a23, h, c);
            if (l < 3) hr[j] = h;
            else Y[((size_t)(e0 + el) * 24) * 8 + j] = f2bf(h);
        }
        for (int t = 1; t < 24; ++t) {
            float xin[8]; ld8(&hr[t * 8], xin);   // prev layer's h_t (off-chain)
            float hp[8];  hshfl(h, hp);           // own h_{t-1} from registers
            f32x2 a01 = b01, a23 = b23;
            gates8p(wx01, wx23, xin, a01, a23);
            gates8p(wh01, wh23, hp, a01, a23);
            cellup(a01, a23, h, c);
            if (l < 3) hr[t * 8 + j] = h;         // next layer's xin
            else Y[((size_t)(e0 + el) * 24 + t) * 8 + j] = f2bf(h);
        }
    }
}

// ------------------------------------------------------- gemm1 (K=192) ----
// Tile 128x128, BK=64, 4 waves; wave tile 64x64 as 2x2 of mfma_32x32x16.
template <int KDIM>
__device__ __forceinline__ void gemm_body(const ushort* __restrict__ A,
                                          const ushort* __restrict__ W,
                                          const float* __restrict__ bias,
                                          ushort* __restrict__ Hout, int N) {
    __shared__ alignas(16) ushort smem[16384];
    ushort* As = smem;            // [128][64] swizzled
    ushort* Ws = smem + 8192;

    const int tid = threadIdx.x;
    const int m0 = blockIdx.x * 128;
    const int n0 = blockIdx.y * 128;
    const int lane = tid & 63;
    const int wv = tid >> 6;
    const int wm = (wv & 1) * 64;
    const int wn = (wv >> 1) * 64;
    const int l31 = lane & 31;
    const int kh = lane >> 5;

    // staging: per wave, 4 calls/tensor; call c: rows wv*32 + c*8 + lrow
    const int lrow = lane >> 3;
    const int lchunk = (lane & 7) ^ lrow;          // XOR swizzle at source
    const ushort* Ag = A + (size_t)(m0 + wv * 32 + lrow) * KDIM + lchunk * 8;
    const ushort* Wg = W + (size_t)(n0 + wv * 32 + lrow) * KDIM + lchunk * 8;
    ushort* Ald = As + wv * 2048;
    ushort* Wld = Ws + wv * 2048;

    const int r7 = l31 & 7;
    const int arow0 = (wm + l31) * 64;        // mi=0; mi=1 adds 32*64
    const int brow0 = (wn + l31) * 64;

    f32x16 acc[2][2];
#pragma unroll
    for (int mi = 0; mi < 2; ++mi)
#pragma unroll
        for (int ni = 0; ni < 2; ++ni)
#pragma unroll
            for (int r = 0; r < 16; ++r) acc[mi][ni][r] = 0.f;

    for (int k0 = 0; k0 < KDIM; k0 += 64) {
#pragma unroll
        for (int c = 0; c < 4; ++c)
            g2l16(Ag + (size_t)c * 8 * KDIM + k0, Ald + c * 512);
#pragma unroll
        for (int c = 0; c < 4; ++c)
            g2l16(Wg + (size_t)c * 8 * KDIM + k0, Wld + c * 512);
        __syncthreads();

#pragma unroll
        for (int ks = 0; ks < 4; ++ks) {
            const int ck = ((ks * 2 + kh) ^ r7) * 8;
            bf16x8 afr[2], bfr[2];
#pragma unroll
            for (int mi = 0; mi < 2; ++mi)
                afr[mi] = *(const bf16x8*)&As[arow0 + mi * 2048 + ck];
#pragma unroll
            for (int ni = 0; ni < 2; ++ni)
                bfr[ni] = *(const bf16x8*)&Ws[brow0 + ni * 2048 + ck];
#pragma unroll
            for (int mi = 0; mi < 2; ++mi)
#pragma unroll
                for (int ni = 0; ni < 2; ++ni)
                    acc[mi][ni] = __builtin_amdgcn_mfma_f32_32x32x16_bf16(afr[mi], bfr[ni],
                                                                         acc[mi][ni], 0, 0, 0);
        }
        __syncthreads();
    }

#pragma unroll
    for (int ni = 0; ni < 2; ++ni) {
        const int col = n0 + wn + ni * 32 + l31;
        const float b = bias[col];
#pragma unroll
        for (int mi = 0; mi < 2; ++mi)
#pragma unroll
            for (int r = 0; r < 16; ++r) {
                const int row = m0 + wm + mi * 32 + (r & 3) + 8 * (r >> 2) + 4 * kh;
                Hout[(size_t)row * N + col] = f2bf(fmaxf(acc[mi][ni][r] + b, 0.f));
            }
    }
}

__global__ __launch_bounds__(256, 4) void gemm1_kernel(const ushort* __restrict__ A,
                                                       const ushort* __restrict__ W,
                                                       const float* __restrict__ bias,
                                                       ushort* __restrict__ Hout, int N) {
    gemm_body<192>(A, W, bias, Hout, N);
}

// ---------------------------------------------- gemm2: 256^2 8-phase -----
template <int OFFB>
__device__ __forceinline__ bf16x8 dsr(unsigned a) {
    bf16x8 r;
    asm volatile("ds_read_b128 %0, %1 offset:%2"
                 : "=v"(r) : "v"(a), "i"(OFFB));
    return r;
}
// one 8-MFMA sub-cluster: quad (QA,QB), k-slice KS
template <int QA, int QB, int KS>
__device__ __forceinline__ void mma_sub(f32x4 acc[8][4], const bf16x8 afr[8],
                                        const bf16x8 br[4]) {
#pragma unroll
    for (int mi = 0; mi < 4; ++mi)
#pragma unroll
        for (int ni = 0; ni < 2; ++ni)
            acc[QA * 4 + mi][QB * 2 + ni] = __builtin_amdgcn_mfma_f32_16x16x32_bf16(
                afr[mi * 2 + KS], br[ni * 2 + KS], acc[QA * 4 + mi][QB * 2 + ni],
                0, 0, 0);
}

#define SBAR()  __builtin_amdgcn_s_barrier()
#define SCHED0() __builtin_amdgcn_sched_barrier(0)
#define LGKM(N) do { asm volatile("s_waitcnt lgkmcnt(" #N ")"); SCHED0(); } while (0)
#define VMC(N)  do { asm volatile("s_waitcnt vmcnt(" #N ")" ::: "memory"); } while (0)
#define PRIO1() __builtin_amdgcn_s_setprio(1)
#define PRIO0() do { __builtin_amdgcn_s_setprio(0); SCHED0(); } while (0)

__global__ __launch_bounds__(512) void gemm2_kernel(const ushort* __restrict__ A,
                                                    const ushort* __restrict__ W,
                                                    const float* __restrict__ bias,
                                                    const float* __restrict__ W3,
                                                    float* __restrict__ outf) {
    // LDS: 2 K-tile double buffer, [256 rows][64 k] bf16 per tensor per buf.
    // A0 @0, B0 @32768, A1 @65536, B1 @98304 (byte offsets). 128 KiB.
    __shared__ alignas(16) ushort smem[65536];
    __shared__ alignas(16) float w3s[1040];   // W3[4][256] at pitch 260

    const int tid = threadIdx.x;
    // bijective XCD swizzle (512 % 8 == 0)
    const int wg = ((int)blockIdx.x & 7) * 64 + ((int)blockIdx.x >> 3);
    const int m0 = (wg >> 3) << 8;
    const int n0 = (wg & 7) << 8;

    const int lane = tid & 63;
    const int wv = tid >> 6;

    // ---- staging addressing (pre-swizzled global source, linear LDS dest)
    const int lrow = tid >> 3;                         // 0..63 rows per call
    const int lc8 = ((tid & 7) ^ (lrow & 7)) << 3;     // swizzled k-chunk
    const ushort* Ag = A + (size_t)(m0 + lrow) * 1024 + lc8;
    const ushort* Bg = W + (size_t)(n0 + lrow) * 1024 + lc8;
    ushort* const sA0 = smem;
    ushort* const sB0 = smem + 16384;
    ushort* const sA1 = smem + 32768;
    ushort* const sB1 = smem + 49152;
    const int srow64 = (wv << 3) * 64;                 // wave's LDS row base

    // ---- frag addressing: phys chunk = logical ^ (row&7); byte addrs
    const int l15 = lane & 15, kq = lane >> 4, r7 = l15 & 7;
    const int wM = wv >> 2, wN = wv & 3;               // 2M x 4N waves
    const unsigned sbase = (unsigned)(unsigned long long)&smem[0];
    const unsigned pc0B = (unsigned)((kq ^ r7) << 4);
    const unsigned pc1B = pc0B ^ 64u;                  // chunk ^= 4 (ks=1)
    const unsigned aRowB = (unsigned)((wM * 128 + l15) * 128);
    const unsigned bRowB = (unsigned)((wN * 64 + l15) * 128);
    const unsigned aA0p0 = sbase + aRowB + pc0B;
    const unsigned aA0p1 = sbase + aRowB + pc1B;
    const unsigned aA1p0 = aA0p0 + 65536u;
    const unsigned aA1p1 = aA0p1 + 65536u;
    const unsigned bB0p0 = sbase + 32768u + bRowB + pc0B;
    const unsigned bB0p1 = sbase + 32768u + bRowB + pc1B;
    const unsigned bB1p0 = bB0p0 + 65536u;
    const unsigned bB1p1 = bB0p1 + 65536u;

    auto stA = [&](int buf, int h, int kt) {           // stage A half-tile
        ushort* b = buf ? sA1 : sA0;
#pragma unroll
        for (int c = 0; c < 2; ++c)
            g2l16(Ag + (size_t)(h * 128 + c * 64) * 1024 + kt * 64,
                  b + (h * 128 + c * 64) * 64 + srow64);
    };
    auto stB = [&](int buf, int h, int kt) {           // stage B half-tile
        ushort* b = buf ? sB1 : sB0;
#pragma unroll
        for (int c = 0; c < 2; ++c)
            g2l16(Bg + (size_t)(h * 128 + c * 64) * 1024 + kt * 64,
                  b + (h * 128 + c * 64) * 64 + srow64);
    };

    f32x4 acc[8][4];
#pragma unroll
    for (int i = 0; i < 8; ++i)
#pragma unroll
        for (int j = 0; j < 4; ++j)
#pragma unroll
            for (int r = 0; r < 4; ++r) acc[i][j][r] = 0.f;

    // W3 -> LDS + bias -> regs (before staging; lgkmcnt(0) drains ds_writes)
#pragma unroll
    for (int i = 0; i < 2; ++i) {
        int idx = tid + i * 512;
        w3s[(idx >> 8) * 260 + (idx & 255)] = W3[(size_t)(idx >> 8) * 2048 + n0 + (idx & 255)];
    }
    float bias4[4];
#pragma unroll
    for (int ni = 0; ni < 4; ++ni) bias4[ni] = bias[n0 + wN * 64 + ni * 16 + l15];

    // prologue: buf0 kt0 full (8) + buf1 kt1 B both halves + A h0 (6).
    // A1h1(kt1) comes from it0's P1 stage. VMC(6) lands buf0, leaves buf1's 6.
    stA(0, 0, 0); stA(0, 1, 0); stB(0, 0, 0); stB(0, 1, 0);
    stB(1, 0, 1); stB(1, 1, 1); stA(1, 0, 1);
    asm volatile("s_waitcnt lgkmcnt(0)");              // w3s ds_writes drained
    VMC(6);
    SBAR(); SCHED0();

    bf16x8 afr[8], b0r[4], b1r[4];
    // P1s0 preload: aLo-ks0 + b0-ks0 (6 reads)
    afr[0] = dsr<0>(aA0p0);    afr[2] = dsr<2048>(aA0p0);
    afr[4] = dsr<4096>(aA0p0); afr[6] = dsr<6144>(aA0p0);
    b0r[0] = dsr<0>(bB0p0);    b0r[2] = dsr<2048>(bB0p0);

#pragma unroll 1
    for (int it = 0; it < 8; ++it) {
        const int k1 = 2 * it + 1, k2 = 2 * it + 2, k3 = 2 * it + 3;
        const bool nl = (it < 7);
        // ---- P1: quad(0,0) buf0 (aLo+b0) | stage A1h1(k1) ----
        SBAR(); SCHED0();
        afr[1] = dsr<0>(aA0p1);    afr[3] = dsr<2048>(aA0p1);
        afr[5] = dsr<4096>(aA0p1); afr[7] = dsr<6144>(aA0p1);
        b0r[1] = dsr<0>(bB0p1);    b0r[3] = dsr<2048>(bB0p1);
        stA(1, 1, k1);
        LGKM(6); PRIO1(); mma_sub<0, 0, 0>(acc, afr, b0r); PRIO0();
        b1r[0] = dsr<4096>(bB0p0); b1r[2] = dsr<6144>(bB0p0);
        LGKM(2); PRIO1(); mma_sub<0, 0, 1>(acc, afr, b0r); PRIO0();
        // ---- P2: quad(0,1) buf0 (aLo+b1) ----
        SBAR(); SCHED0();
        b1r[1] = dsr<4096>(bB0p1); b1r[3] = dsr<6144>(bB0p1);
        LGKM(2); PRIO1(); mma_sub<0, 1, 0>(acc, afr, b1r); PRIO0();
        afr[0] = dsr<8192>(aA0p0);  afr[2] = dsr<10240>(aA0p0);
        afr[4] = dsr<12288>(aA0p0); afr[6] = dsr<14336>(aA0p0);
        LGKM(4); PRIO1(); mma_sub<0, 1, 1>(acc, afr, b1r); PRIO0();
        // ---- P3: quad(1,1) buf0 (aHi+b1) | stage B0h0(k2) ----
        SBAR(); SCHED0();
        afr[1] = dsr<8192>(aA0p1);  afr[3] = dsr<10240>(aA0p1);
        afr[5] = dsr<12288>(aA0p1); afr[7] = dsr<14336>(aA0p1);
        if (nl) stB(0, 0, k2);
        LGKM(4); PRIO1(); mma_sub<1, 1, 0>(acc, afr, b1r); PRIO0();
        LGKM(0); PRIO1(); mma_sub<1, 1, 1>(acc, afr, b1r); PRIO0();
        // ---- P4: quad(1,0) buf0 (aHi+b0) | wait buf1 | stage B0h1+A0h0(k2) ----
        if (nl) { VMC(2); } else { VMC(0); }
        SBAR(); SCHED0();
        if (nl) { stB(0, 1, k2); stA(0, 0, k2); }
        PRIO1(); mma_sub<1, 0, 0>(acc, afr, b0r); PRIO0();
        afr[0] = dsr<8192>(aA1p0);  afr[2] = dsr<10240>(aA1p0);
        afr[4] = dsr<12288>(aA1p0); afr[6] = dsr<14336>(aA1p0);
        b0r[0] = dsr<0>(bB1p0);     b0r[2] = dsr<2048>(bB1p0);
        PRIO1(); mma_sub<1, 0, 1>(acc, afr, b0r); PRIO0();
        // ---- P5: quad(1,0) buf1 (aHi1+b0_1) | stage A0h1(k2) ----
        SBAR(); SCHED0();
        afr[1] = dsr<8192>(aA1p1);  afr[3] = dsr<10240>(aA1p1);
        afr[5] = dsr<12288>(aA1p1); afr[7] = dsr<14336>(aA1p1);
        b0r[1] = dsr<0>(bB1p1);     b0r[3] = dsr<2048>(bB1p1);
        if (nl) stA(0, 1, k2);
        LGKM(6); PRIO1(); mma_sub<1, 0, 0>(acc, afr, b0r); PRIO0();
        b1r[0] = dsr<4096>(bB1p0); b1r[2] = dsr<6144>(bB1p0);
        LGKM(2); PRIO1(); mma_sub<1, 0, 1>(acc, afr, b0r); PRIO0();
        // ---- P6: quad(1,1) buf1 ----
        SBAR(); SCHED0();
        b1r[1] = dsr<4096>(bB1p1); b1r[3] = dsr<6144>(bB1p1);
        LGKM(2); PRIO1(); mma_sub<1, 1, 0>(acc, afr, b1r); PRIO0();
        afr[0] = dsr<0>(aA1p0);    afr[2] = dsr<2048>(aA1p0);
        afr[4] = dsr<4096>(aA1p0); afr[6] = dsr<6144>(aA1p0);
        LGKM(4); PRIO1(); mma_sub<1, 1, 1>(acc, afr, b1r); PRIO0();
        // ---- P7: quad(0,1) buf1 (aLo1+b1_1) | stage B1h0(k3) ----
        SBAR(); SCHED0();
        afr[1] = dsr<0>(aA1p1);    afr[3] = dsr<2048>(aA1p1);
        afr[5] = dsr<4096>(aA1p1); afr[7] = dsr<6144>(aA1p1);
        if (nl) stB(1, 0, k3);
        LGKM(4); PRIO1(); mma_sub<0, 1, 0>(acc, afr, b1r); PRIO0();
        LGKM(0); PRIO1(); mma_sub<0, 1, 1>(acc, afr, b1r); PRIO0();
        // ---- P8: quad(0,0) buf1 (aLo1+b0_1) | wait buf0-k2 | stage B1h1+A1h0(k3) ----
        if (nl) { VMC(2); }
        SBAR(); SCHED0();
        if (nl) { stB(1, 1, k3); stA(1, 0, k3); }
        PRIO1(); mma_sub<0, 0, 0>(acc, afr, b0r); PRIO0();
        if (nl) {   // P1s0 of next iter (buf0, k2)
            afr[0] = dsr<0>(aA0p0);    afr[2] = dsr<2048>(aA0p0);
            afr[4] = dsr<4096>(aA0p0); afr[6] = dsr<6144>(aA0p0);
            b0r[0] = dsr<0>(bB0p0);    b0r[2] = dsr<2048>(bB0p0);
        }
        PRIO1(); mma_sub<0, 0, 1>(acc, afr, b0r); PRIO0();
    }

    // ---- fused relu + W3 epilogue: 4 slab passes over Cs[64][260] f32 ----
    // De-broadcast dot: lane j8 owns cols {j8*4 + 32k, k=0..7} (disjoint,
    // bank = 4*drow + 4*j8 -> conflict-free). One Cs read serves 4 outputs.
    float* Cs = (float*)smem;
    const int drow = tid >> 3;            // 0..63
    const int j8 = tid & 7;               // col-interleave lane
    __syncthreads();
#pragma unroll
    for (int s = 0; s < 4; ++s) {
        if (wM == (s >> 1)) {
            const int mb = (s & 1) * 4;
#pragma unroll
            for (int mi = 0; mi < 4; ++mi)
#pragma unroll
                for (int ni = 0; ni < 4; ++ni) {
                    f32x4 v = acc[mb + mi][ni];
                    const int cbase = (mi * 16 + kq * 4) * 260 + wN * 64 + ni * 16 + l15;
#pragma unroll
                    for (int r = 0; r < 4; ++r)
                        Cs[cbase + r * 260] = fmaxf(v[r] + bias4[ni], 0.f);
                }
        }
        __syncthreads();
        {
            const float* crow = &Cs[drow * 260 + j8 * 4];
            f32x4 pp = {0.f, 0.f, 0.f, 0.f};
#pragma unroll
            for (int k = 0; k < 8; ++k) {
                f32x4 cv = *(const f32x4*)(crow + k * 32);
#pragma unroll
                for (int q = 0; q < 4; ++q) {
                    f32x4 wv4 = *(const f32x4*)(&w3s[q * 260 + j8 * 4 + k * 32]);
                    pp[q] += cv[0] * wv4[0] + cv[1] * wv4[1] + cv[2] * wv4[2] + cv[3] * wv4[3];
                }
            }
#pragma unroll
            for (int m = 1; m < 8; m <<= 1) {
#pragma unroll
                for (int q = 0; q < 4; ++q) pp[q] += __shfl_xor(pp[q], m);
            }
            const float pv = (j8 == 0) ? pp[0] : (j8 == 1) ? pp[1]
                           : (j8 == 2) ? pp[2] : pp[3];
            if (j8 < 4)
                atomicAdd(&outf[(size_t)(m0 + s * 64 + drow) * 4 + j8], pv);
        }
        __syncthreads();
    }
}

// -------------------------------------------------------------- launch ----
extern "C" void kernel_launch(void* const* d_in, const int* in_sizes, int n_in,
                              void* d_out, int out_size, void* d_ws, size_t ws_size,
                              hipStream_t stream) {
    const float* x = (const float*)d_in[0];
    LstmW w;
    for (int l = 0; l < 4; ++l) {
        w.wih[l] = (const float*)d_in[1 + 4 * l];
        w.whh[l] = (const float*)d_in[2 + 4 * l];
        w.bih[l] = (const float*)d_in[3 + 4 * l];
        w.bhh[l] = (const float*)d_in[4 + 4 * l];
    }
    const float* Wd1 = (const float*)d_in[17];
    const float* bd1 = (const float*)d_in[18];
    const float* Wd2 = (const float*)d_in[19];
    const float* bd2 = (const float*)d_in[20];
    const float* Wd3 = (const float*)d_in[21];
    const float* bd3 = (const float*)d_in[22];
    float* out = (float*)d_out;

    ushort* Y   = (ushort*)d_ws;
    ushort* H1  = (ushort*)((char*)d_ws + 6291456);
    ushort* W1b = (ushort*)((char*)d_ws + 39845888);
    ushort* W2b = (ushort*)((char*)d_ws + 40239104);

    pre_kernel<<<1072, 256, 0, stream>>>(x, w, Y, Wd1, Wd2, W1b, W2b, bd3, out);
    gemm1_kernel<<<dim3(128, 8), 256, 0, stream>>>(Y, W1b, bd1, H1, 1024);
    gemm2_kernel<<<512, 512, 0, stream>>>(H1, W2b, bd2, Wd3, out);
}